// Round 8
// baseline (1190.119 us; speedup 1.0000x reference)
//
#include <hip/hip_runtime.h>
#include <hip/hip_bf16.h>

#define N_NODES 50000
#define N_EDGES 1600000
#define N_GRAPHS 256
#define NEG_SLOPE 0.2f
#define BN_EPS 1e-5f

typedef __hip_bfloat16 bf16;

__device__ __forceinline__ float b2f(bf16 v){ return __bfloat162float(v); }
__device__ __forceinline__ bf16 f2b(float v){ return __float2bfloat16(v); }
__device__ __forceinline__ float us2f(unsigned short u){ return __uint_as_float(((unsigned)u)<<16); }
__device__ __forceinline__ unsigned short f2us(float v){ bf16 b = f2b(v); return *(unsigned short*)&b; }
__device__ __forceinline__ float ldF(const void* p, size_t i, int m){
  return m ? ((const float*)p)[i] : b2f(((const bf16*)p)[i]);
}
__device__ __forceinline__ float sane(float v){
  return (v == v && fabsf(v) < 1e30f) ? v : 0.f;
}
__device__ __forceinline__ float sel4(const float v[4], int h){
  float r = v[0];
  r = (h==1) ? v[1] : r;
  r = (h==2) ? v[2] : r;
  r = (h==3) ? v[3] : r;
  return r;
}

// block-level dtype detection: scans first 1024 halfwords of x under bf16 view.
// f32-packed data -> ~45% wild values; true bf16 normals stay in (1e-6,1e4).
__device__ int detect_mode_block(const void* x){
  __shared__ int s_ins;
  if(threadIdx.x == 0) s_ins = 0;
  __syncthreads();
  const unsigned short* u = (const unsigned short*)x;
  int c = 0;
  for(int i = threadIdx.x; i < 1024; i += blockDim.x){
    float v = fabsf(us2f(u[i]));
    if(!(v > 1e-6f && v < 1e4f)) c++;
  }
  if(c) atomicAdd(&s_ins, c);
  __syncthreads();
  return (s_ins > 128) ? 1 : 0;   // 1 => f32
}

// ---------------- weight bank conversion (detect fused) ----------------
#define NSEG 33
struct Bank { const void* p[NSEG]; int n[NSEG]; int off[NSEG]; };

__global__ void k_convert(Bank b, const void* xdet, float* out){
  int m = detect_mode_block(xdet);
  int seg = blockIdx.y;
  int i = blockIdx.x*256 + threadIdx.x;
  if(i < b.n[seg]) out[b.off[seg] + i] = ldF(b.p[seg], i, m);
}

// convert x -> bf16 (4 elements/thread)
__global__ void k_cvt_x(const void* x, bf16* xb){
  int m = detect_mode_block(x);
  int i4 = blockIdx.x*256 + threadIdx.x;
  if(i4 >= N_NODES*16) return;
  if(m){
    float4 v = ((const float4*)x)[i4];
    ((ushort4*)xb)[i4] = make_ushort4(f2us(v.x), f2us(v.y), f2us(v.z), f2us(v.w));
  } else {
    ((ushort4*)xb)[i4] = ((const ushort4*)x)[i4];
  }
}

__global__ void k_we(const float* __restrict__ We1, const float* __restrict__ ae1,
                     const float* __restrict__ We2, const float* __restrict__ ae2,
                     float* __restrict__ w_e){
  int t = threadIdx.x;
  if(t < 32){
    int h = t >> 3, k = t & 7;
    float s = 0.f;
    for(int d=0;d<64;d++) s += We1[k*256 + h*64 + d] * ae1[h*64 + d];
    w_e[t] = s;
  } else if(t < 40){
    int k = t - 32;
    float s = 0.f;
    for(int d=0;d<64;d++) s += We2[k*64 + d] * ae2[d];
    w_e[t] = s;
  }
}

// ---------------- CSR build ----------------
__global__ void k_count(const int* __restrict__ dst, int* __restrict__ cnt){
  int e = blockIdx.x*256 + threadIdx.x;
  if(e < N_EDGES){
    int d = dst[e]; if((unsigned)d >= N_NODES) d = 0;
    atomicAdd(&cnt[d], 1);
  }
}

__global__ void k_blocksum(const int* __restrict__ cnt, int* __restrict__ bsum){
  __shared__ int s[256];
  int i = blockIdx.x*256 + threadIdx.x;
  s[threadIdx.x] = (i < N_NODES) ? cnt[i] : 0;
  __syncthreads();
  for(int o=128;o>0;o>>=1){ if(threadIdx.x<o) s[threadIdx.x]+=s[threadIdx.x+o]; __syncthreads(); }
  if(threadIdx.x==0) bsum[blockIdx.x]=s[0];
}

__global__ void k_scan_bsum(const int* __restrict__ bsum, int* __restrict__ bofs, int nb){
  __shared__ int s[256];
  int t = threadIdx.x;
  s[t] = (t<nb) ? bsum[t] : 0;
  __syncthreads();
  for(int o=1;o<256;o<<=1){ int v=(t>=o)?s[t-o]:0; __syncthreads(); s[t]+=v; __syncthreads(); }
  bofs[t] = (t==0) ? 0 : s[t-1];
}

// scan + dinv fused
__global__ void k_scan_write(const int* __restrict__ cnt, const int* __restrict__ bofs,
                             int* __restrict__ rp, float* __restrict__ dinv){
  __shared__ int s[256];
  int t = threadIdx.x; int i = blockIdx.x*256 + t;
  int v = (i<N_NODES) ? cnt[i] : 0;
  s[t]=v; __syncthreads();
  for(int o=1;o<256;o<<=1){ int a=(t>=o)?s[t-o]:0; __syncthreads(); s[t]+=a; __syncthreads(); }
  if(i<N_NODES){
    rp[i+1] = s[t] + bofs[blockIdx.x];
    dinv[i] = rsqrtf((float)v + 1.f);
  }
  if(i==0) rp[0]=0;
}

// fill CSR: packed 16B record per slot = {src, edot4[4] bf16, edot1 bf16}
__global__ void k_fill(const int* __restrict__ src, const int* __restrict__ dst,
                       const int* __restrict__ rp, int* __restrict__ fill,
                       const void* __restrict__ ea, const void* __restrict__ xdet,
                       const float* __restrict__ w_e,
                       int4* __restrict__ epk){
  int m = detect_mode_block(xdet);
  int e = blockIdx.x*256 + threadIdx.x;
  if(e >= N_EDGES) return;
  int d = dst[e]; if((unsigned)d >= N_NODES) d = 0;
  int p = atomicAdd(&fill[d], 1);
  int slot = rp[d] + p;
  if((unsigned)slot >= N_EDGES) return;
  int sv = src[e]; if((unsigned)sv >= N_NODES) sv = 0;
  float a[8];
  if(m){
    const float* eaf = (const float*)ea;
    float4 lo = *(const float4*)&eaf[(size_t)e*8];
    float4 hi = *(const float4*)&eaf[(size_t)e*8 + 4];
    a[0]=lo.x; a[1]=lo.y; a[2]=lo.z; a[3]=lo.w;
    a[4]=hi.x; a[5]=hi.y; a[6]=hi.z; a[7]=hi.w;
  } else {
    #pragma unroll
    for(int k=0;k<8;k++) a[k] = b2f(((const bf16*)ea)[(size_t)e*8 + k]);
  }
  unsigned d4[4];
  #pragma unroll
  for(int h=0;h<4;h++){
    float s = 0.f;
    #pragma unroll
    for(int k=0;k<8;k++) s += a[k]*w_e[h*8+k];
    d4[h] = f2us(s);
  }
  float s1 = 0.f;
  #pragma unroll
  for(int k=0;k<8;k++) s1 += a[k]*w_e[32+k];
  int4 pk;
  pk.x = sv;
  pk.y = (int)(d4[0] | (d4[1] << 16));
  pk.z = (int)(d4[2] | (d4[3] << 16));
  pk.w = (int)(unsigned)f2us(s1);
  epk[slot] = pk;
}

// ---------------- GEMM layer 1: bf16 x [N,64] @ W1[64,256], 4 heads in one block,
// A-tile staged once; fused als4/ald4 epilogue ----------------
__global__ __launch_bounds__(256) void k_gemm1(
    const bf16* __restrict__ xb, const float* __restrict__ W1,
    const float* __restrict__ as1, const float* __restrict__ ad1,
    bf16* __restrict__ hp, float* __restrict__ als4, float* __restrict__ ald4, int M)
{
  __shared__ float As[64][68];
  __shared__ float Ws[64][64];
  const int tid = threadIdx.x;
  const int bm  = blockIdx.x * 64;
  const int tx  = tid & 15;
  const int ty  = tid >> 4;
  // stage A once (KIN=64)
  #pragma unroll
  for(int f = tid; f < 1024; f += 256){
    int r = f >> 4, kq = f & 15;
    int row = bm + r;
    float4 v = make_float4(0.f,0.f,0.f,0.f);
    if(row < M){
      const bf16* p = &xb[(size_t)row*64 + 4*kq];
      v = make_float4(b2f(p[0]), b2f(p[1]), b2f(p[2]), b2f(p[3]));
    }
    *(float4*)&As[r][4*kq] = v;
  }
  for(int h = 0; h < 4; h++){
    #pragma unroll
    for(int g = tid; g < 1024; g += 256){
      int kr = g >> 4, jq = g & 15;
      *(float4*)&Ws[kr][4*jq] = *(const float4*)&W1[(size_t)kr*256 + h*64 + 4*jq];
    }
    __syncthreads();
    float acc[4][4] = {};
    #pragma unroll
    for(int k = 0; k < 64; k += 4){
      float4 av[4], wv[4];
      #pragma unroll
      for(int r=0;r<4;r++) av[r] = *(const float4*)&As[4*ty + r][k];
      #pragma unroll
      for(int kk=0;kk<4;kk++) wv[kk] = *(const float4*)&Ws[k + kk][4*tx];
      #pragma unroll
      for(int r=0;r<4;r++){
        const float a0=av[r].x, a1=av[r].y, a2=av[r].z, a3=av[r].w;
        acc[r][0] += a0*wv[0].x + a1*wv[1].x + a2*wv[2].x + a3*wv[3].x;
        acc[r][1] += a0*wv[0].y + a1*wv[1].y + a2*wv[2].y + a3*wv[3].y;
        acc[r][2] += a0*wv[0].z + a1*wv[1].z + a2*wv[2].z + a3*wv[3].z;
        acc[r][3] += a0*wv[0].w + a1*wv[1].w + a2*wv[2].w + a3*wv[3].w;
      }
    }
    __syncthreads();
    // epilogue: write hp slice + fused alpha dots
    float4 a_s = *(const float4*)&as1[h*64 + 4*tx];
    float4 a_d = *(const float4*)&ad1[h*64 + 4*tx];
    #pragma unroll
    for(int r=0;r<4;r++){
      int row = bm + 4*ty + r;
      bool ok = row < M;
      if(ok){
        bf16* Cb = hp;
        ushort4 u = make_ushort4(f2us(acc[r][0]), f2us(acc[r][1]), f2us(acc[r][2]), f2us(acc[r][3]));
        *(ushort4*)&Cb[(size_t)row*256 + h*64 + 4*tx] = u;
      }
      float ssp = ok ? (acc[r][0]*a_s.x + acc[r][1]*a_s.y + acc[r][2]*a_s.z + acc[r][3]*a_s.w) : 0.f;
      float sdp = ok ? (acc[r][0]*a_d.x + acc[r][1]*a_d.y + acc[r][2]*a_d.z + acc[r][3]*a_d.w) : 0.f;
      #pragma unroll
      for(int o=1;o<16;o<<=1){ ssp += __shfl_xor(ssp, o); sdp += __shfl_xor(sdp, o); }
      if(ok && tx == 0){ als4[row*4 + h] = ssp; ald4[row*4 + h] = sdp; }
    }
  }
}

// ---------------- GEMM layers 2-4: f32 in [N,KIN] (+opt BN-ReLU), bf16 out [N,64],
// optional fused alpha-dot epilogue ----------------
template<int KIN, bool BNF, bool ALD>
__global__ __launch_bounds__(256) void k_gemm_t(
    const float* __restrict__ A, const float* __restrict__ W,
    bf16* __restrict__ C, int M,
    const float* __restrict__ bnsums, const float* __restrict__ bng, const float* __restrict__ bnb,
    const float* __restrict__ asv, const float* __restrict__ adv,
    float* __restrict__ als, float* __restrict__ ald)
{
  __shared__ float As[64][68];
  __shared__ float Ws[64][64];
  const int tid = threadIdx.x;
  const int bm  = blockIdx.x * 64;
  const int tx  = tid & 15;
  const int ty  = tid >> 4;
  const float invN = 1.0f / (float)N_NODES;
  float acc[4][4] = {};

  for(int k0 = 0; k0 < KIN; k0 += 64){
    #pragma unroll
    for(int f = tid; f < 1024; f += 256){
      int r = f >> 4, kq = f & 15;
      int row = bm + r;
      float4 v = make_float4(0.f,0.f,0.f,0.f);
      if(row < M) v = *(const float4*)&A[(size_t)row*KIN + k0 + 4*kq];
      if(BNF){
        int c = k0 + 4*kq;
        float vv[4] = {v.x, v.y, v.z, v.w};
        #pragma unroll
        for(int j=0;j<4;j++){
          int cc = c + j;
          float mean = bnsums[cc]*invN;
          float var = fmaxf(bnsums[KIN+cc]*invN - mean*mean, 0.f);
          float y = (sane(vv[j])-mean)*rsqrtf(var + BN_EPS)*bng[cc] + bnb[cc];
          vv[j] = fmaxf(y, 0.f);
        }
        v = make_float4(vv[0], vv[1], vv[2], vv[3]);
      }
      *(float4*)&As[r][4*kq] = v;
    }
    #pragma unroll
    for(int g = tid; g < 1024; g += 256){
      int kr = g >> 4, jq = g & 15;
      *(float4*)&Ws[kr][4*jq] = *(const float4*)&W[(size_t)(k0+kr)*64 + 4*jq];
    }
    __syncthreads();
    #pragma unroll
    for(int k = 0; k < 64; k += 4){
      float4 av[4], wv[4];
      #pragma unroll
      for(int r=0;r<4;r++) av[r] = *(const float4*)&As[4*ty + r][k];
      #pragma unroll
      for(int kk=0;kk<4;kk++) wv[kk] = *(const float4*)&Ws[k + kk][4*tx];
      #pragma unroll
      for(int r=0;r<4;r++){
        const float a0=av[r].x, a1=av[r].y, a2=av[r].z, a3=av[r].w;
        acc[r][0] += a0*wv[0].x + a1*wv[1].x + a2*wv[2].x + a3*wv[3].x;
        acc[r][1] += a0*wv[0].y + a1*wv[1].y + a2*wv[2].y + a3*wv[3].y;
        acc[r][2] += a0*wv[0].z + a1*wv[1].z + a2*wv[2].z + a3*wv[3].z;
        acc[r][3] += a0*wv[0].w + a1*wv[1].w + a2*wv[2].w + a3*wv[3].w;
      }
    }
    __syncthreads();
  }
  float4 a_s, a_d;
  if(ALD){
    a_s = *(const float4*)&asv[4*tx];
    a_d = *(const float4*)&adv[4*tx];
  }
  #pragma unroll
  for(int r=0;r<4;r++){
    int row = bm + 4*ty + r;
    bool ok = row < M;
    if(ok){
      ushort4 u = make_ushort4(f2us(acc[r][0]), f2us(acc[r][1]), f2us(acc[r][2]), f2us(acc[r][3]));
      *(ushort4*)&C[(size_t)row*64 + 4*tx] = u;
    }
    if(ALD){
      float ssp = ok ? (acc[r][0]*a_s.x + acc[r][1]*a_s.y + acc[r][2]*a_s.z + acc[r][3]*a_s.w) : 0.f;
      float sdp = ok ? (acc[r][0]*a_d.x + acc[r][1]*a_d.y + acc[r][2]*a_d.z + acc[r][3]*a_d.w) : 0.f;
      #pragma unroll
      for(int o=1;o<16;o<<=1){ ssp += __shfl_xor(ssp, o); sdp += __shfl_xor(sdp, o); }
      if(ok && tx == 0){ als[row] = ssp; ald[row] = sdp; }
    }
  }
}

// ---------------- fused 4-head GAT aggregate: ONE WAVE per node ----------------
__global__ __launch_bounds__(64) void k_gat_agg4(
    const int* __restrict__ rp, const int4* __restrict__ epk,
    const bf16* __restrict__ hp,                 // [N,256]
    const float* __restrict__ als4, const float* __restrict__ ald4,
    const float* __restrict__ bias256, float* __restrict__ out1){
  int n = blockIdx.x; int t = threadIdx.x;
  int head = t >> 4;
  __shared__ int   ssrc[64];
  __shared__ float swt[64][4];
  int s0 = rp[n], e0 = rp[n+1];
  if((unsigned)s0 > N_EDGES){ s0=0; e0=0; }
  if(e0 < s0 || (unsigned)e0 > N_EDGES) e0 = s0;
  float4 aldv = *(const float4*)&ald4[n*4];
  float4 alsvn = *(const float4*)&als4[n*4];
  float wsum[4] = {0.f,0.f,0.f,0.f};
  float dsum[4] = {0.f,0.f,0.f,0.f};
  float acc[4]  = {0.f,0.f,0.f,0.f};
  const unsigned short* hpu = (const unsigned short*)hp;

  for(int base = s0; base < e0; base += 64){
    int m = min(64, e0 - base);
    if(t < m){
      int4 pk = epk[base+t];
      int sn = pk.x; if((unsigned)sn >= N_NODES) sn = 0;
      ssrc[t] = sn;
      float edf[4] = {us2f((unsigned short)(pk.y & 0xffff)), us2f((unsigned short)((unsigned)pk.y >> 16)),
                      us2f((unsigned short)(pk.z & 0xffff)), us2f((unsigned short)((unsigned)pk.z >> 16))};
      float4 alss = *(const float4*)&als4[sn*4];
      float alssv[4] = {alss.x, alss.y, alss.z, alss.w};
      float aldvv[4] = {aldv.x, aldv.y, aldv.z, aldv.w};
      float w4[4];
      #pragma unroll
      for(int h=0;h<4;h++){
        float sc = alssv[h] + aldvv[h] + edf[h];
        sc = sc > 0.f ? sc : NEG_SLOPE*sc;
        sc = fminf(sc, 30.f);
        float w = expf(sc);
        w4[h] = w;
        wsum[h] += w; dsum[h] += edf[h];
      }
      *(float4*)&swt[t][0] = make_float4(w4[0], w4[1], w4[2], w4[3]);
    }
    __syncthreads();
    #pragma unroll 4
    for(int i=0;i<m;i++){
      int row = ssrc[i];
      float w = swt[i][head];
      ushort4 u = *(const ushort4*)&hpu[(size_t)row*256 + 4*t];
      acc[0] += w*us2f(u.x); acc[1] += w*us2f(u.y);
      acc[2] += w*us2f(u.z); acc[3] += w*us2f(u.w);
    }
    __syncthreads();
  }
  #pragma unroll
  for(int o=1;o<64;o<<=1){
    #pragma unroll
    for(int h=0;h<4;h++){
      wsum[h] += __shfl_xor(wsum[h], o);
      dsum[h] += __shfl_xor(dsum[h], o);
    }
  }
  float alsnv[4] = {alsvn.x, alsvn.y, alsvn.z, alsvn.w};
  float aldnv[4] = {aldv.x, aldv.y, aldv.z, aldv.w};
  float sEh = sel4(wsum, head), sDh = sel4(dsum, head);
  float deg = (float)(e0 - s0);
  float sdot = deg > 0.f ? sDh/deg : 0.f;
  float sc = sel4(alsnv, head) + sel4(aldnv, head) + sdot;
  sc = sc > 0.f ? sc : NEG_SLOPE*sc;
  sc = fminf(sc, 30.f);
  float wself = expf(sc);
  ushort4 su = *(const ushort4*)&hpu[(size_t)n*256 + 4*t];
  float4 bi = *(const float4*)&bias256[4*t];
  float inv = 1.f/(sEh + wself);
  float4 o4;
  o4.x = (acc[0] + wself*us2f(su.x))*inv + bi.x;
  o4.y = (acc[1] + wself*us2f(su.y))*inv + bi.y;
  o4.z = (acc[2] + wself*us2f(su.z))*inv + bi.z;
  o4.w = (acc[3] + wself*us2f(su.w))*inv + bi.w;
  *(float4*)&out1[(size_t)n*256 + 4*t] = o4;
}

// ---------------- single-head GAT aggregate: ONE WAVE per node, 4 edges/iter ----------------
__global__ __launch_bounds__(64) void k_gat_agg1e(
    const int* __restrict__ rp, const int4* __restrict__ epk,
    const bf16* __restrict__ hp,                 // [N,64]
    const float* __restrict__ als, const float* __restrict__ ald,
    const float* __restrict__ bias64, float* __restrict__ out){
  int n = blockIdx.x; int t = threadIdx.x;
  int eg = t >> 4, cq = t & 15;
  __shared__ float sw[64];
  __shared__ int   ssrc[64];
  int s0 = rp[n], e0 = rp[n+1];
  if((unsigned)s0 > N_EDGES){ s0=0; e0=0; }
  if(e0 < s0 || (unsigned)e0 > N_EDGES) e0 = s0;
  float aldn = ald[n];
  float wsum_l = 0.f, dsum_l = 0.f;
  float acc[4] = {0.f,0.f,0.f,0.f};
  const unsigned short* hpu = (const unsigned short*)hp;
  for(int base = s0; base < e0; base += 64){
    int m = min(64, e0 - base);
    if(t < m){
      int4 pk = epk[base+t];
      int sn = pk.x; if((unsigned)sn >= N_NODES) sn = 0;
      ssrc[t] = sn;
      float ed = us2f((unsigned short)(pk.w & 0xffff));
      float sc = als[sn] + aldn + ed;
      sc = sc > 0.f ? sc : NEG_SLOPE*sc;
      sc = fminf(sc, 30.f);
      float w = expf(sc);
      sw[t] = w;
      wsum_l += w; dsum_l += ed;
    }
    __syncthreads();
    #pragma unroll 2
    for(int i=0;i<m;i+=4){
      int j = i + eg;
      if(j < m){
        int row = ssrc[j];
        float w = sw[j];
        ushort4 u = *(const ushort4*)&hpu[(size_t)row*64 + 4*cq];
        acc[0] += w*us2f(u.x); acc[1] += w*us2f(u.y);
        acc[2] += w*us2f(u.z); acc[3] += w*us2f(u.w);
      }
    }
    __syncthreads();
  }
  #pragma unroll
  for(int o=1;o<64;o<<=1){ wsum_l += __shfl_xor(wsum_l, o); dsum_l += __shfl_xor(dsum_l, o); }
  #pragma unroll
  for(int q=0;q<4;q++){ acc[q] += __shfl_xor(acc[q], 16); acc[q] += __shfl_xor(acc[q], 32); }
  if(t < 16){
    float deg = (float)(e0 - s0);
    float sdot = deg > 0.f ? dsum_l/deg : 0.f;
    float sc = als[n] + aldn + sdot;
    sc = sc > 0.f ? sc : NEG_SLOPE*sc;
    sc = fminf(sc, 30.f);
    float wself = expf(sc);
    ushort4 su = *(const ushort4*)&hpu[(size_t)n*64 + 4*cq];
    float4 bi = *(const float4*)&bias64[4*cq];
    float inv = 1.f/(wsum_l + wself);
    float4 o4;
    o4.x = (acc[0] + wself*us2f(su.x))*inv + bi.x;
    o4.y = (acc[1] + wself*us2f(su.y))*inv + bi.y;
    o4.z = (acc[2] + wself*us2f(su.z))*inv + bi.z;
    o4.w = (acc[3] + wself*us2f(su.w))*inv + bi.w;
    *(float4*)&out[(size_t)n*64 + 4*cq] = o4;
  }
}

// ---------------- GCN aggregate: ONE WAVE per node, 4 edges/iter ----------------
__global__ __launch_bounds__(64) void k_gcn_agg(
    const int* __restrict__ rp, const int4* __restrict__ epk,
    const float* __restrict__ dinv, const bf16* __restrict__ gp,
    const float* __restrict__ bias, float* __restrict__ out){
  int n = blockIdx.x; int t = threadIdx.x;
  int eg = t >> 4, cq = t & 15;
  __shared__ float sw[64];
  __shared__ int   ssrc[64];
  int s0 = rp[n], e0 = rp[n+1];
  if((unsigned)s0 > N_EDGES){ s0=0; e0=0; }
  if(e0 < s0 || (unsigned)e0 > N_EDGES) e0 = s0;
  float dn = dinv[n];
  float acc[4] = {0.f,0.f,0.f,0.f};
  const unsigned short* gpu = (const unsigned short*)gp;
  for(int base = s0; base < e0; base += 64){
    int m = min(64, e0 - base);
    if(t < m){
      int sn = epk[base+t].x; if((unsigned)sn >= N_NODES) sn = 0;
      ssrc[t]=sn; sw[t]=dinv[sn];
    }
    __syncthreads();
    #pragma unroll 2
    for(int i=0;i<m;i+=4){
      int j = i + eg;
      if(j < m){
        int row = ssrc[j];
        float w = sw[j];
        ushort4 u = *(const ushort4*)&gpu[(size_t)row*64 + 4*cq];
        acc[0] += w*us2f(u.x); acc[1] += w*us2f(u.y);
        acc[2] += w*us2f(u.z); acc[3] += w*us2f(u.w);
      }
    }
    __syncthreads();
  }
  #pragma unroll
  for(int q=0;q<4;q++){ acc[q] += __shfl_xor(acc[q], 16); acc[q] += __shfl_xor(acc[q], 32); }
  if(t < 16){
    ushort4 su = *(const ushort4*)&gpu[(size_t)n*64 + 4*cq];
    float4 bi = *(const float4*)&bias[4*cq];
    float4 o4;
    o4.x = dn*(acc[0] + dn*us2f(su.x)) + bi.x;
    o4.y = dn*(acc[1] + dn*us2f(su.y)) + bi.y;
    o4.z = dn*(acc[2] + dn*us2f(su.z)) + bi.z;
    o4.w = dn*(acc[3] + dn*us2f(su.w)) + bi.w;
    *(float4*)&out[(size_t)n*64 + 4*cq] = o4;
  }
}

// ---------------- BN stats ----------------
template<int C>
__global__ void k_colstats(const float* __restrict__ X, float* __restrict__ sums){
  constexpr int RPB = 128;
  constexpr int RSTEP = 256 / C;
  int c = threadIdx.x % C;
  int r0 = threadIdx.x / C;
  int rbeg = blockIdx.x * RPB;
  int rend = min(N_NODES, rbeg + RPB);
  float s = 0.f, q = 0.f;
  for(int r = rbeg + r0; r < rend; r += RSTEP){
    float v = sane(X[(size_t)r*C + c]);
    s += v; q += v*v;
  }
  atomicAdd(&sums[c], s);
  atomicAdd(&sums[C + c], q);
}

// ---------------- mean pool with fused BN+ReLU ----------------
__global__ __launch_bounds__(64) void k_pool3(
    const float* __restrict__ h, const int* __restrict__ batch,
    const float* __restrict__ sums, const float* __restrict__ g4,
    const float* __restrict__ b4,
    float* __restrict__ psum, float* __restrict__ pcnt){
  int t = threadIdx.x;
  int n0 = blockIdx.x * 256;
  int n1 = min(N_NODES, n0 + 256);
  if(n0 >= n1) return;
  const float invN = 1.0f / (float)N_NODES;
  float mean = sums[t]*invN;
  float var = fmaxf(sums[64+t]*invN - mean*mean, 0.f);
  float rstd = rsqrtf(var + BN_EPS);
  float gg = g4[t], bb = b4[t];
  int cur = batch[n0]; if((unsigned)cur >= N_GRAPHS) cur = 0;
  float acc = 0.f; int cl = 0;
  for(int n = n0; n < n1; n++){
    int g = batch[n]; if((unsigned)g >= N_GRAPHS) g = 0;
    if(g != cur){
      atomicAdd(&psum[cur*64 + t], acc);
      if(t == 0) atomicAdd(&pcnt[cur], (float)cl);
      acc = 0.f; cl = 0; cur = g;
    }
    float y = (sane(h[(size_t)n*64 + t])-mean)*rstd*gg + bb;
    acc += fmaxf(y, 0.f);
    cl++;
  }
  atomicAdd(&psum[cur*64 + t], acc);
  if(t == 0) atomicAdd(&pcnt[cur], (float)cl);
}

// ---------------- head MLPs + output ----------------
__device__ __forceinline__ void stO(void* o, size_t i, float v, int m){
  if(m) ((float*)o)[i] = v; else ((bf16*)o)[i] = f2b(v);
}

__global__ __launch_bounds__(128) void k_head(
    const float* __restrict__ psum, const float* __restrict__ pcnt,
    const float* __restrict__ exf,
    const float* __restrict__ Wex1, const float* __restrict__ bex1,
    const float* __restrict__ Wex2, const float* __restrict__ bex2,
    const float* __restrict__ Wc1, const float* __restrict__ bc1,
    const float* __restrict__ Wc2, const float* __restrict__ bc2,
    const void* __restrict__ xdet, void* __restrict__ dout){
  int m0 = detect_mode_block(xdet);
  int g = blockIdx.x; int t = threadIdx.x;
  __shared__ float ci[128];
  __shared__ float e1[64];
  __shared__ float comb[128];
  __shared__ float red[128];
  if(t < 64){
    float c = fmaxf(pcnt[g], 1.f);
    float xp = sane(psum[g*64 + t]) / c;
    ci[t] = xp;
    stO(dout, 256 + (size_t)g*64 + t, xp, m0);
  } else {
    int j = t - 64;
    float s = bex1[j];
    for(int k=0;k<32;k++) s += exf[g*32 + k] * Wex1[k*64 + j];
    e1[j] = fmaxf(s, 0.f);
  }
  __syncthreads();
  if(t >= 64){
    int j = t - 64;
    float s = bex2[j];
    for(int k=0;k<64;k++) s += e1[k] * Wex2[k*64 + j];
    ci[64 + j] = fmaxf(s, 0.f);
  }
  __syncthreads();
  {
    float s = bc1[t];
    for(int k=0;k<128;k++) s += ci[k] * Wc1[k*128 + t];
    s = fmaxf(s, 0.f);
    comb[t] = s;
    stO(dout, 256 + 16384 + (size_t)g*128 + t, s, m0);
  }
  __syncthreads();
  red[t] = comb[t] * Wc2[t];
  __syncthreads();
  for(int o=64;o>0;o>>=1){ if(t<o) red[t]+=red[t+o]; __syncthreads(); }
  if(t==0) stO(dout, g, red[0] + bc2[0], m0);
}

// ---------------- launch ----------------
extern "C" void kernel_launch(void* const* d_in, const int* in_sizes, int n_in,
                              void* d_out, int out_size, void* d_ws, size_t ws_size,
                              hipStream_t stream){
  const void* x    = d_in[0];
  const void* ea   = d_in[1];
  const int* ei    = (const int*)d_in[3];
  const int* batch = (const int*)d_in[4];
  const int* src = ei;
  const int* dst = ei + N_EDGES;

  char* base = (char*)d_ws;
  size_t off = 0;
  auto alloc = [&](size_t bytes) -> void* {
    void* r = base + off;
    off += (bytes + 255) & ~(size_t)255;
    return r;
  };
  int*   cnt    = (int*)  alloc((size_t)N_NODES*4);
  int*   fill   = (int*)  alloc((size_t)N_NODES*4);
  float* bnstat = (float*)alloc(4096);
  float* pool   = (float*)alloc((size_t)(N_GRAPHS*64 + N_GRAPHS)*4);
  size_t zbytes = off;
  int*   rp      = (int*)  alloc((size_t)(N_NODES+1)*4);
  int*   bsum    = (int*)  alloc(256*4);
  int*   bofs    = (int*)  alloc(256*4);
  int4*  epk     = (int4*) alloc((size_t)N_EDGES*16);
  float* dinv    = (float*)alloc((size_t)N_NODES*4);
  float* w_e     = (float*)alloc(64*4);
  float* als4    = (float*)alloc((size_t)N_NODES*4*4);
  float* ald4    = (float*)alloc((size_t)N_NODES*4*4);
  float* wbank   = (float*)alloc(80000*4);
  bf16*  xb      = (bf16*) alloc((size_t)N_NODES*64*2);
  bf16*  hp      = (bf16*) alloc((size_t)N_NODES*256*2);
  float* out1    = (float*)alloc((size_t)N_NODES*256*4);

  float* out2 = out1;
  float* out3 = out1 + (size_t)N_NODES*64;
  float* out4 = out1 + (size_t)N_NODES*128;
  float* bn1 = bnstat;
  float* bn2 = bnstat + 512;
  float* bn3 = bnstat + 640;
  float* bn4 = bnstat + 768;
  float* psum = pool;
  float* pcnt = pool + N_GRAPHS*64;

  const int segidx[NSEG] = {2, 5,6,7,8,9,10,11,12, 13,14,15,16,17,18,19,20,
                            21,22,23,24, 25,26,27,28, 29,30,31,32, 33,34,35,36};
  const int segn[NSEG] = {8192, 16384,256,256,2048,256,256,256,256,
                          16384,64,64,512,64,64,64,64,
                          4096,64,64,64, 4096,64,64,64,
                          2048,64,4096,64, 16384,128,128,1};
  Bank bk;
  int offs[NSEG]; int acc0 = 0;
  for(int i=0;i<NSEG;i++){ bk.p[i]=d_in[segidx[i]]; bk.n[i]=segn[i]; bk.off[i]=acc0; offs[i]=acc0; acc0+=segn[i]; }
  const float* f_exf = wbank + offs[0];
  const float* fW1 = wbank+offs[1]; const float* fas1 = wbank+offs[2]; const float* fad1 = wbank+offs[3];
  const float* fWe1= wbank+offs[4]; const float* fae1 = wbank+offs[5]; const float* fb1  = wbank+offs[6];
  const float* fg1 = wbank+offs[7]; const float* fbe1 = wbank+offs[8];
  const float* fW2 = wbank+offs[9]; const float* fas2 = wbank+offs[10]; const float* fad2 = wbank+offs[11];
  const float* fWe2= wbank+offs[12]; const float* fae2 = wbank+offs[13]; const float* fb2 = wbank+offs[14];
  const float* fg2 = wbank+offs[15]; const float* fbe2 = wbank+offs[16];
  const float* fWg1= wbank+offs[17]; const float* fbg1 = wbank+offs[18]; const float* fg3 = wbank+offs[19];
  const float* fbe3= wbank+offs[20];
  const float* fWg2= wbank+offs[21]; const float* fbg2 = wbank+offs[22]; const float* fg4 = wbank+offs[23];
  const float* fbe4= wbank+offs[24];
  const float* fWex1=wbank+offs[25]; const float* fbex1= wbank+offs[26];
  const float* fWex2=wbank+offs[27]; const float* fbex2= wbank+offs[28];
  const float* fWc1= wbank+offs[29]; const float* fbc1 = wbank+offs[30];
  const float* fWc2= wbank+offs[31]; const float* fbc2 = wbank+offs[32];

  const int nbN  = (N_NODES + 255)/256;
  const int nbE  = (N_EDGES + 255)/256;
  const int nbT  = (N_NODES + 63)/64;

  hipMemsetAsync(d_ws, 0, zbytes, stream);
  {
    dim3 g((16384+255)/256, NSEG);
    k_convert<<<g,256,0,stream>>>(bk, x, wbank);
  }
  k_cvt_x<<<(N_NODES*16+255)/256,256,0,stream>>>(x, xb);
  k_we<<<1,64,0,stream>>>(fWe1, fae1, fWe2, fae2, w_e);
  k_count<<<nbE,256,0,stream>>>(dst, cnt);
  k_blocksum<<<nbN,256,0,stream>>>(cnt, bsum);
  k_scan_bsum<<<1,256,0,stream>>>(bsum, bofs, nbN);
  k_scan_write<<<nbN,256,0,stream>>>(cnt, bofs, rp, dinv);
  k_fill<<<nbE,256,0,stream>>>(src, dst, rp, fill, ea, x, w_e, epk);

  // GAT layer 1 (4 heads, single-pass GEMM + fused alpha dots)
  k_gemm1<<<nbT,256,0,stream>>>(xb, fW1, fas1, fad1, hp, als4, ald4, N_NODES);
  k_gat_agg4<<<N_NODES,64,0,stream>>>(rp, epk, hp, als4, ald4, fb1, out1);
  k_colstats<256><<<(N_NODES+127)/128,256,0,stream>>>(out1, bn1);

  // GAT layer 2 (1 head) — BN1+ReLU fused into A-staging, alpha dots fused
  k_gemm_t<256,true,true><<<nbT,256,0,stream>>>(out1, fW2, hp, N_NODES,
                                                bn1, fg1, fbe1, fas2, fad2, als4, ald4);
  k_gat_agg1e<<<N_NODES,64,0,stream>>>(rp, epk, hp, als4, ald4, fb2, out2);
  k_colstats<64><<<(N_NODES+127)/128,256,0,stream>>>(out2, bn2);

  // GCN layer 1 — BN2+ReLU fused
  k_gemm_t<64,true,false><<<nbT,256,0,stream>>>(out2, fWg1, hp, N_NODES,
                                                bn2, fg2, fbe2, nullptr, nullptr, nullptr, nullptr);
  k_gcn_agg<<<N_NODES,64,0,stream>>>(rp, epk, dinv, hp, fbg1, out3);
  k_colstats<64><<<(N_NODES+127)/128,256,0,stream>>>(out3, bn3);

  // GCN layer 2 — BN3+ReLU fused
  k_gemm_t<64,true,false><<<nbT,256,0,stream>>>(out3, fWg2, hp, N_NODES,
                                                bn3, fg3, fbe3, nullptr, nullptr, nullptr, nullptr);
  k_gcn_agg<<<N_NODES,64,0,stream>>>(rp, epk, dinv, hp, fbg2, out4);
  k_colstats<64><<<(N_NODES+127)/128,256,0,stream>>>(out4, bn4);

  // pool (BN4+ReLU fused) + head
  k_pool3<<<nbN,64,0,stream>>>(out4, batch, bn4, fg4, fbe4, psum, pcnt);
  k_head<<<N_GRAPHS,128,0,stream>>>(psum, pcnt, f_exf, fWex1, fbex1, fWex2, fbex2,
                                    fWc1, fbc1, fWc2, fbc2, x, (void*)d_out);
}

// Round 9
// 1006.308 us; speedup vs baseline: 1.1827x; 1.1827x over previous
//
#include <hip/hip_runtime.h>
#include <hip/hip_bf16.h>

#define N_NODES 50000
#define N_EDGES 1600000
#define N_GRAPHS 256
#define NEG_SLOPE 0.2f
#define BN_EPS 1e-5f

typedef __hip_bfloat16 bf16;

__device__ __forceinline__ float b2f(bf16 v){ return __bfloat162float(v); }
__device__ __forceinline__ bf16 f2b(float v){ return __float2bfloat16(v); }
__device__ __forceinline__ float us2f(unsigned short u){ return __uint_as_float(((unsigned)u)<<16); }
__device__ __forceinline__ unsigned short f2us(float v){ bf16 b = f2b(v); return *(unsigned short*)&b; }
__device__ __forceinline__ float ldF(const void* p, size_t i, int m){
  return m ? ((const float*)p)[i] : b2f(((const bf16*)p)[i]);
}
__device__ __forceinline__ float sane(float v){
  return (v == v && fabsf(v) < 1e30f) ? v : 0.f;
}
__device__ __forceinline__ float sel4(const float v[4], int h){
  float r = v[0];
  r = (h==1) ? v[1] : r;
  r = (h==2) ? v[2] : r;
  r = (h==3) ? v[3] : r;
  return r;
}

// block-level dtype detection: scans first 1024 halfwords of x under bf16 view.
__device__ int detect_mode_block(const void* x){
  __shared__ int s_ins;
  if(threadIdx.x == 0) s_ins = 0;
  __syncthreads();
  const unsigned short* u = (const unsigned short*)x;
  int c = 0;
  for(int i = threadIdx.x; i < 1024; i += blockDim.x){
    float v = fabsf(us2f(u[i]));
    if(!(v > 1e-6f && v < 1e4f)) c++;
  }
  if(c) atomicAdd(&s_ins, c);
  __syncthreads();
  return (s_ins > 128) ? 1 : 0;   // 1 => f32
}

// ---------------- weight bank conversion (detect fused) ----------------
#define NSEG 33
struct Bank { const void* p[NSEG]; int n[NSEG]; int off[NSEG]; };

__global__ void k_convert(Bank b, const void* xdet, float* out){
  int m = detect_mode_block(xdet);
  int seg = blockIdx.y;
  int i = blockIdx.x*256 + threadIdx.x;
  if(i < b.n[seg]) out[b.off[seg] + i] = ldF(b.p[seg], i, m);
}

// convert x -> bf16 (4 elements/thread)
__global__ void k_cvt_x(const void* x, bf16* xb){
  int m = detect_mode_block(x);
  int i4 = blockIdx.x*256 + threadIdx.x;
  if(i4 >= N_NODES*16) return;
  if(m){
    float4 v = ((const float4*)x)[i4];
    ((ushort4*)xb)[i4] = make_ushort4(f2us(v.x), f2us(v.y), f2us(v.z), f2us(v.w));
  } else {
    ((ushort4*)xb)[i4] = ((const ushort4*)x)[i4];
  }
}

__global__ void k_we(const float* __restrict__ We1, const float* __restrict__ ae1,
                     const float* __restrict__ We2, const float* __restrict__ ae2,
                     float* __restrict__ w_e){
  int t = threadIdx.x;
  if(t < 32){
    int h = t >> 3, k = t & 7;
    float s = 0.f;
    for(int d=0;d<64;d++) s += We1[k*256 + h*64 + d] * ae1[h*64 + d];
    w_e[t] = s;
  } else if(t < 40){
    int k = t - 32;
    float s = 0.f;
    for(int d=0;d<64;d++) s += We2[k*64 + d] * ae2[d];
    w_e[t] = s;
  }
}

// ---------------- CSR build ----------------
__global__ void k_count(const int* __restrict__ dst, int* __restrict__ cnt){
  int e = blockIdx.x*256 + threadIdx.x;
  if(e < N_EDGES){
    int d = dst[e]; if((unsigned)d >= N_NODES) d = 0;
    atomicAdd(&cnt[d], 1);
  }
}

__global__ void k_blocksum(const int* __restrict__ cnt, int* __restrict__ bsum){
  __shared__ int s[256];
  int i = blockIdx.x*256 + threadIdx.x;
  s[threadIdx.x] = (i < N_NODES) ? cnt[i] : 0;
  __syncthreads();
  for(int o=128;o>0;o>>=1){ if(threadIdx.x<o) s[threadIdx.x]+=s[threadIdx.x+o]; __syncthreads(); }
  if(threadIdx.x==0) bsum[blockIdx.x]=s[0];
}

__global__ void k_scan_bsum(const int* __restrict__ bsum, int* __restrict__ bofs, int nb){
  __shared__ int s[256];
  int t = threadIdx.x;
  s[t] = (t<nb) ? bsum[t] : 0;
  __syncthreads();
  for(int o=1;o<256;o<<=1){ int v=(t>=o)?s[t-o]:0; __syncthreads(); s[t]+=v; __syncthreads(); }
  bofs[t] = (t==0) ? 0 : s[t-1];
}

// scan + dinv fused
__global__ void k_scan_write(const int* __restrict__ cnt, const int* __restrict__ bofs,
                             int* __restrict__ rp, float* __restrict__ dinv){
  __shared__ int s[256];
  int t = threadIdx.x; int i = blockIdx.x*256 + t;
  int v = (i<N_NODES) ? cnt[i] : 0;
  s[t]=v; __syncthreads();
  for(int o=1;o<256;o<<=1){ int a=(t>=o)?s[t-o]:0; __syncthreads(); s[t]+=a; __syncthreads(); }
  if(i<N_NODES){
    rp[i+1] = s[t] + bofs[blockIdx.x];
    dinv[i] = rsqrtf((float)v + 1.f);
  }
  if(i==0) rp[0]=0;
}

// fill CSR: packed 16B record per slot = {src, edot4[4] bf16, edot1 bf16}
__global__ void k_fill(const int* __restrict__ src, const int* __restrict__ dst,
                       const int* __restrict__ rp, int* __restrict__ fill,
                       const void* __restrict__ ea, const void* __restrict__ xdet,
                       const float* __restrict__ w_e,
                       int4* __restrict__ epk){
  int m = detect_mode_block(xdet);
  int e = blockIdx.x*256 + threadIdx.x;
  if(e >= N_EDGES) return;
  int d = dst[e]; if((unsigned)d >= N_NODES) d = 0;
  int p = atomicAdd(&fill[d], 1);
  int slot = rp[d] + p;
  if((unsigned)slot >= N_EDGES) return;
  int sv = src[e]; if((unsigned)sv >= N_NODES) sv = 0;
  float a[8];
  if(m){
    const float* eaf = (const float*)ea;
    float4 lo = *(const float4*)&eaf[(size_t)e*8];
    float4 hi = *(const float4*)&eaf[(size_t)e*8 + 4];
    a[0]=lo.x; a[1]=lo.y; a[2]=lo.z; a[3]=lo.w;
    a[4]=hi.x; a[5]=hi.y; a[6]=hi.z; a[7]=hi.w;
  } else {
    #pragma unroll
    for(int k=0;k<8;k++) a[k] = b2f(((const bf16*)ea)[(size_t)e*8 + k]);
  }
  unsigned d4[4];
  #pragma unroll
  for(int h=0;h<4;h++){
    float s = 0.f;
    #pragma unroll
    for(int k=0;k<8;k++) s += a[k]*w_e[h*8+k];
    d4[h] = f2us(s);
  }
  float s1 = 0.f;
  #pragma unroll
  for(int k=0;k<8;k++) s1 += a[k]*w_e[32+k];
  int4 pk;
  pk.x = sv;
  pk.y = (int)(d4[0] | (d4[1] << 16));
  pk.z = (int)(d4[2] | (d4[3] << 16));
  pk.w = (int)(unsigned)f2us(s1);
  epk[slot] = pk;
}

// ---------------- GEMM layer 1: hp[:, h*64..] = xb[N,64] @ W1[:, h*64..] ----------------
// grid (nbT, 4); controlled unroll; launch_bounds caps VGPR at ~170 (3 blocks/CU).
__global__ __launch_bounds__(256, 3) void k_gemmA(
    const bf16* __restrict__ xb, const float* __restrict__ W1,
    bf16* __restrict__ hp, int M)
{
  __shared__ float As[64][68];
  __shared__ float Ws[64][64];
  const int tid = threadIdx.x;
  const int bm  = blockIdx.x * 64;
  const int h   = blockIdx.y;
  const int tx  = tid & 15;
  const int ty  = tid >> 4;
  float acc[4][4] = {};

  #pragma unroll
  for(int f = tid; f < 1024; f += 256){
    int r = f >> 4, kq = f & 15;
    int row = bm + r;
    float4 v = make_float4(0.f,0.f,0.f,0.f);
    if(row < M){
      ushort4 u = *(const ushort4*)&xb[(size_t)row*64 + 4*kq];
      v = make_float4(us2f(u.x), us2f(u.y), us2f(u.z), us2f(u.w));
    }
    *(float4*)&As[r][4*kq] = v;
  }
  #pragma unroll
  for(int g = tid; g < 1024; g += 256){
    int kr = g >> 4, jq = g & 15;
    *(float4*)&Ws[kr][4*jq] = *(const float4*)&W1[(size_t)kr*256 + h*64 + 4*jq];
  }
  __syncthreads();
  #pragma unroll 2
  for(int k = 0; k < 64; k += 4){
    float4 av[4], wv[4];
    #pragma unroll
    for(int r=0;r<4;r++) av[r] = *(const float4*)&As[4*ty + r][k];
    #pragma unroll
    for(int kk=0;kk<4;kk++) wv[kk] = *(const float4*)&Ws[k + kk][4*tx];
    #pragma unroll
    for(int r=0;r<4;r++){
      const float a0=av[r].x, a1=av[r].y, a2=av[r].z, a3=av[r].w;
      acc[r][0] += a0*wv[0].x + a1*wv[1].x + a2*wv[2].x + a3*wv[3].x;
      acc[r][1] += a0*wv[0].y + a1*wv[1].y + a2*wv[2].y + a3*wv[3].y;
      acc[r][2] += a0*wv[0].z + a1*wv[1].z + a2*wv[2].z + a3*wv[3].z;
      acc[r][3] += a0*wv[0].w + a1*wv[1].w + a2*wv[2].w + a3*wv[3].w;
    }
  }
  #pragma unroll
  for(int r=0;r<4;r++){
    int row = bm + 4*ty + r;
    if(row < M){
      ushort4 u = make_ushort4(f2us(acc[r][0]), f2us(acc[r][1]), f2us(acc[r][2]), f2us(acc[r][3]));
      *(ushort4*)&hp[(size_t)row*256 + h*64 + 4*tx] = u;
    }
  }
}

// ---------------- GEMM layers 2-4: f32 A [N,KIN] (+opt BN-ReLU) -> bf16 C [N,64] ----------------
template<int KIN, bool BNF>
__global__ __launch_bounds__(256, 3) void k_gemmB(
    const float* __restrict__ A, const float* __restrict__ W,
    bf16* __restrict__ C, int M,
    const float* __restrict__ bnsums, const float* __restrict__ bng, const float* __restrict__ bnb)
{
  __shared__ float As[64][68];
  __shared__ float Ws[64][64];
  const int tid = threadIdx.x;
  const int bm  = blockIdx.x * 64;
  const int tx  = tid & 15;
  const int ty  = tid >> 4;
  const float invN = 1.0f / (float)N_NODES;
  float acc[4][4] = {};

  for(int k0 = 0; k0 < KIN; k0 += 64){
    #pragma unroll
    for(int f = tid; f < 1024; f += 256){
      int r = f >> 4, kq = f & 15;
      int row = bm + r;
      float4 v = make_float4(0.f,0.f,0.f,0.f);
      if(row < M) v = *(const float4*)&A[(size_t)row*KIN + k0 + 4*kq];
      if(BNF){
        int c = k0 + 4*kq;
        float vv[4] = {v.x, v.y, v.z, v.w};
        #pragma unroll
        for(int j=0;j<4;j++){
          int cc = c + j;
          float mean = bnsums[cc]*invN;
          float var = fmaxf(bnsums[KIN+cc]*invN - mean*mean, 0.f);
          float y = (sane(vv[j])-mean)*rsqrtf(var + BN_EPS)*bng[cc] + bnb[cc];
          vv[j] = fmaxf(y, 0.f);
        }
        v = make_float4(vv[0], vv[1], vv[2], vv[3]);
      }
      *(float4*)&As[r][4*kq] = v;
    }
    #pragma unroll
    for(int g = tid; g < 1024; g += 256){
      int kr = g >> 4, jq = g & 15;
      *(float4*)&Ws[kr][4*jq] = *(const float4*)&W[(size_t)(k0+kr)*64 + 4*jq];
    }
    __syncthreads();
    #pragma unroll 2
    for(int k = 0; k < 64; k += 4){
      float4 av[4], wv[4];
      #pragma unroll
      for(int r=0;r<4;r++) av[r] = *(const float4*)&As[4*ty + r][k];
      #pragma unroll
      for(int kk=0;kk<4;kk++) wv[kk] = *(const float4*)&Ws[k + kk][4*tx];
      #pragma unroll
      for(int r=0;r<4;r++){
        const float a0=av[r].x, a1=av[r].y, a2=av[r].z, a3=av[r].w;
        acc[r][0] += a0*wv[0].x + a1*wv[1].x + a2*wv[2].x + a3*wv[3].x;
        acc[r][1] += a0*wv[0].y + a1*wv[1].y + a2*wv[2].y + a3*wv[3].y;
        acc[r][2] += a0*wv[0].z + a1*wv[1].z + a2*wv[2].z + a3*wv[3].z;
        acc[r][3] += a0*wv[0].w + a1*wv[1].w + a2*wv[2].w + a3*wv[3].w;
      }
    }
    __syncthreads();
  }
  #pragma unroll
  for(int r=0;r<4;r++){
    int row = bm + 4*ty + r;
    if(row < M){
      ushort4 u = make_ushort4(f2us(acc[r][0]), f2us(acc[r][1]), f2us(acc[r][2]), f2us(acc[r][3]));
      *(ushort4*)&C[(size_t)row*64 + 4*tx] = u;
    }
  }
}

// ---------------- alpha dots ----------------
__global__ void k_al4(const bf16* __restrict__ hp, const float* __restrict__ asrc,
                      const float* __restrict__ adst,
                      float* __restrict__ als4, float* __restrict__ ald4){
  int idx = blockIdx.x*256 + threadIdx.x;
  if(idx >= N_NODES*4) return;
  int n = idx >> 2, h = idx & 3;
  const unsigned short* row = (const unsigned short*)hp + (size_t)n*256 + h*64;
  float ss=0.f, sd=0.f;
  #pragma unroll
  for(int q=0;q<16;q++){
    ushort4 u = *(const ushort4*)&row[4*q];
    float4 a_s = *(const float4*)&asrc[h*64 + 4*q];
    float4 a_d = *(const float4*)&adst[h*64 + 4*q];
    float v0=us2f(u.x), v1=us2f(u.y), v2=us2f(u.z), v3=us2f(u.w);
    ss += v0*a_s.x + v1*a_s.y + v2*a_s.z + v3*a_s.w;
    sd += v0*a_d.x + v1*a_d.y + v2*a_d.z + v3*a_d.w;
  }
  als4[idx]=ss; ald4[idx]=sd;
}

__global__ void k_al1(const bf16* __restrict__ hp, const float* __restrict__ asrc,
                      const float* __restrict__ adst,
                      float* __restrict__ als, float* __restrict__ ald){
  int n = blockIdx.x*256 + threadIdx.x;
  if(n >= N_NODES) return;
  const unsigned short* row = (const unsigned short*)hp + (size_t)n*64;
  float ss=0.f, sd=0.f;
  #pragma unroll
  for(int q=0;q<16;q++){
    ushort4 u = *(const ushort4*)&row[4*q];
    float4 a_s = *(const float4*)&asrc[4*q];
    float4 a_d = *(const float4*)&adst[4*q];
    float v0=us2f(u.x), v1=us2f(u.y), v2=us2f(u.z), v3=us2f(u.w);
    ss += v0*a_s.x + v1*a_s.y + v2*a_s.z + v3*a_s.w;
    sd += v0*a_d.x + v1*a_d.y + v2*a_d.z + v3*a_d.w;
  }
  als[n]=ss; ald[n]=sd;
}

// ---------------- fused 4-head GAT aggregate: ONE WAVE per node ----------------
__global__ __launch_bounds__(64) void k_gat_agg4(
    const int* __restrict__ rp, const int4* __restrict__ epk,
    const bf16* __restrict__ hp,                 // [N,256]
    const float* __restrict__ als4, const float* __restrict__ ald4,
    const float* __restrict__ bias256, float* __restrict__ out1){
  int n = blockIdx.x; int t = threadIdx.x;
  int head = t >> 4;
  __shared__ int   ssrc[64];
  __shared__ float swt[64][4];
  int s0 = rp[n], e0 = rp[n+1];
  if((unsigned)s0 > N_EDGES){ s0=0; e0=0; }
  if(e0 < s0 || (unsigned)e0 > N_EDGES) e0 = s0;
  float4 aldv = *(const float4*)&ald4[n*4];
  float4 alsvn = *(const float4*)&als4[n*4];
  float wsum[4] = {0.f,0.f,0.f,0.f};
  float dsum[4] = {0.f,0.f,0.f,0.f};
  float acc[4]  = {0.f,0.f,0.f,0.f};
  const unsigned short* hpu = (const unsigned short*)hp;

  for(int base = s0; base < e0; base += 64){
    int m = min(64, e0 - base);
    if(t < m){
      int4 pk = epk[base+t];
      int sn = pk.x; if((unsigned)sn >= N_NODES) sn = 0;
      ssrc[t] = sn;
      float edf[4] = {us2f((unsigned short)(pk.y & 0xffff)), us2f((unsigned short)((unsigned)pk.y >> 16)),
                      us2f((unsigned short)(pk.z & 0xffff)), us2f((unsigned short)((unsigned)pk.z >> 16))};
      float4 alss = *(const float4*)&als4[sn*4];
      float alssv[4] = {alss.x, alss.y, alss.z, alss.w};
      float aldvv[4] = {aldv.x, aldv.y, aldv.z, aldv.w};
      float w4[4];
      #pragma unroll
      for(int h=0;h<4;h++){
        float sc = alssv[h] + aldvv[h] + edf[h];
        sc = sc > 0.f ? sc : NEG_SLOPE*sc;
        sc = fminf(sc, 30.f);
        float w = expf(sc);
        w4[h] = w;
        wsum[h] += w; dsum[h] += edf[h];
      }
      *(float4*)&swt[t][0] = make_float4(w4[0], w4[1], w4[2], w4[3]);
    }
    __syncthreads();
    #pragma unroll 4
    for(int i=0;i<m;i++){
      int row = ssrc[i];
      float w = swt[i][head];
      ushort4 u = *(const ushort4*)&hpu[(size_t)row*256 + 4*t];
      acc[0] += w*us2f(u.x); acc[1] += w*us2f(u.y);
      acc[2] += w*us2f(u.z); acc[3] += w*us2f(u.w);
    }
    __syncthreads();
  }
  #pragma unroll
  for(int o=1;o<64;o<<=1){
    #pragma unroll
    for(int h=0;h<4;h++){
      wsum[h] += __shfl_xor(wsum[h], o);
      dsum[h] += __shfl_xor(dsum[h], o);
    }
  }
  float alsnv[4] = {alsvn.x, alsvn.y, alsvn.z, alsvn.w};
  float aldnv[4] = {aldv.x, aldv.y, aldv.z, aldv.w};
  float sEh = sel4(wsum, head), sDh = sel4(dsum, head);
  float deg = (float)(e0 - s0);
  float sdot = deg > 0.f ? sDh/deg : 0.f;
  float sc = sel4(alsnv, head) + sel4(aldnv, head) + sdot;
  sc = sc > 0.f ? sc : NEG_SLOPE*sc;
  sc = fminf(sc, 30.f);
  float wself = expf(sc);
  ushort4 su = *(const ushort4*)&hpu[(size_t)n*256 + 4*t];
  float4 bi = *(const float4*)&bias256[4*t];
  float inv = 1.f/(sEh + wself);
  float4 o4;
  o4.x = (acc[0] + wself*us2f(su.x))*inv + bi.x;
  o4.y = (acc[1] + wself*us2f(su.y))*inv + bi.y;
  o4.z = (acc[2] + wself*us2f(su.z))*inv + bi.z;
  o4.w = (acc[3] + wself*us2f(su.w))*inv + bi.w;
  *(float4*)&out1[(size_t)n*256 + 4*t] = o4;
}

// ---------------- single-head GAT aggregate: ONE WAVE per node, 4 edges/iter ----------------
__global__ __launch_bounds__(64) void k_gat_agg1e(
    const int* __restrict__ rp, const int4* __restrict__ epk,
    const bf16* __restrict__ hp,                 // [N,64]
    const float* __restrict__ als, const float* __restrict__ ald,
    const float* __restrict__ bias64, float* __restrict__ out){
  int n = blockIdx.x; int t = threadIdx.x;
  int eg = t >> 4, cq = t & 15;
  __shared__ float sw[64];
  __shared__ int   ssrc[64];
  int s0 = rp[n], e0 = rp[n+1];
  if((unsigned)s0 > N_EDGES){ s0=0; e0=0; }
  if(e0 < s0 || (unsigned)e0 > N_EDGES) e0 = s0;
  float aldn = ald[n];
  float wsum_l = 0.f, dsum_l = 0.f;
  float acc[4] = {0.f,0.f,0.f,0.f};
  const unsigned short* hpu = (const unsigned short*)hp;
  for(int base = s0; base < e0; base += 64){
    int m = min(64, e0 - base);
    if(t < m){
      int4 pk = epk[base+t];
      int sn = pk.x; if((unsigned)sn >= N_NODES) sn = 0;
      ssrc[t] = sn;
      float ed = us2f((unsigned short)(pk.w & 0xffff));
      float sc = als[sn] + aldn + ed;
      sc = sc > 0.f ? sc : NEG_SLOPE*sc;
      sc = fminf(sc, 30.f);
      float w = expf(sc);
      sw[t] = w;
      wsum_l += w; dsum_l += ed;
    }
    __syncthreads();
    #pragma unroll 2
    for(int i=0;i<m;i+=4){
      int j = i + eg;
      if(j < m){
        int row = ssrc[j];
        float w = sw[j];
        ushort4 u = *(const ushort4*)&hpu[(size_t)row*64 + 4*cq];
        acc[0] += w*us2f(u.x); acc[1] += w*us2f(u.y);
        acc[2] += w*us2f(u.z); acc[3] += w*us2f(u.w);
      }
    }
    __syncthreads();
  }
  #pragma unroll
  for(int o=1;o<64;o<<=1){ wsum_l += __shfl_xor(wsum_l, o); dsum_l += __shfl_xor(dsum_l, o); }
  #pragma unroll
  for(int q=0;q<4;q++){ acc[q] += __shfl_xor(acc[q], 16); acc[q] += __shfl_xor(acc[q], 32); }
  if(t < 16){
    float deg = (float)(e0 - s0);
    float sdot = deg > 0.f ? dsum_l/deg : 0.f;
    float sc = als[n] + aldn + sdot;
    sc = sc > 0.f ? sc : NEG_SLOPE*sc;
    sc = fminf(sc, 30.f);
    float wself = expf(sc);
    ushort4 su = *(const ushort4*)&hpu[(size_t)n*64 + 4*cq];
    float4 bi = *(const float4*)&bias64[4*cq];
    float inv = 1.f/(wsum_l + wself);
    float4 o4;
    o4.x = (acc[0] + wself*us2f(su.x))*inv + bi.x;
    o4.y = (acc[1] + wself*us2f(su.y))*inv + bi.y;
    o4.z = (acc[2] + wself*us2f(su.z))*inv + bi.z;
    o4.w = (acc[3] + wself*us2f(su.w))*inv + bi.w;
    *(float4*)&out[(size_t)n*64 + 4*cq] = o4;
  }
}

// ---------------- GCN aggregate: ONE WAVE per node, 4 edges/iter ----------------
__global__ __launch_bounds__(64) void k_gcn_agg(
    const int* __restrict__ rp, const int4* __restrict__ epk,
    const float* __restrict__ dinv, const bf16* __restrict__ gp,
    const float* __restrict__ bias, float* __restrict__ out){
  int n = blockIdx.x; int t = threadIdx.x;
  int eg = t >> 4, cq = t & 15;
  __shared__ float sw[64];
  __shared__ int   ssrc[64];
  int s0 = rp[n], e0 = rp[n+1];
  if((unsigned)s0 > N_EDGES){ s0=0; e0=0; }
  if(e0 < s0 || (unsigned)e0 > N_EDGES) e0 = s0;
  float dn = dinv[n];
  float acc[4] = {0.f,0.f,0.f,0.f};
  const unsigned short* gpu = (const unsigned short*)gp;
  for(int base = s0; base < e0; base += 64){
    int m = min(64, e0 - base);
    if(t < m){
      int sn = epk[base+t].x; if((unsigned)sn >= N_NODES) sn = 0;
      ssrc[t]=sn; sw[t]=dinv[sn];
    }
    __syncthreads();
    #pragma unroll 2
    for(int i=0;i<m;i+=4){
      int j = i + eg;
      if(j < m){
        int row = ssrc[j];
        float w = sw[j];
        ushort4 u = *(const ushort4*)&gpu[(size_t)row*64 + 4*cq];
        acc[0] += w*us2f(u.x); acc[1] += w*us2f(u.y);
        acc[2] += w*us2f(u.z); acc[3] += w*us2f(u.w);
      }
    }
    __syncthreads();
  }
  #pragma unroll
  for(int q=0;q<4;q++){ acc[q] += __shfl_xor(acc[q], 16); acc[q] += __shfl_xor(acc[q], 32); }
  if(t < 16){
    ushort4 su = *(const ushort4*)&gpu[(size_t)n*64 + 4*cq];
    float4 bi = *(const float4*)&bias[4*cq];
    float4 o4;
    o4.x = dn*(acc[0] + dn*us2f(su.x)) + bi.x;
    o4.y = dn*(acc[1] + dn*us2f(su.y)) + bi.y;
    o4.z = dn*(acc[2] + dn*us2f(su.z)) + bi.z;
    o4.w = dn*(acc[3] + dn*us2f(su.w)) + bi.w;
    *(float4*)&out[(size_t)n*64 + 4*cq] = o4;
  }
}

// ---------------- BN stats ----------------
template<int C>
__global__ void k_colstats(const float* __restrict__ X, float* __restrict__ sums){
  constexpr int RPB = 128;
  constexpr int RSTEP = 256 / C;
  int c = threadIdx.x % C;
  int r0 = threadIdx.x / C;
  int rbeg = blockIdx.x * RPB;
  int rend = min(N_NODES, rbeg + RPB);
  float s = 0.f, q = 0.f;
  for(int r = rbeg + r0; r < rend; r += RSTEP){
    float v = sane(X[(size_t)r*C + c]);
    s += v; q += v*v;
  }
  atomicAdd(&sums[c], s);
  atomicAdd(&sums[C + c], q);
}

// ---------------- mean pool with fused BN+ReLU ----------------
__global__ __launch_bounds__(64) void k_pool3(
    const float* __restrict__ h, const int* __restrict__ batch,
    const float* __restrict__ sums, const float* __restrict__ g4,
    const float* __restrict__ b4,
    float* __restrict__ psum, float* __restrict__ pcnt){
  int t = threadIdx.x;
  int n0 = blockIdx.x * 256;
  int n1 = min(N_NODES, n0 + 256);
  if(n0 >= n1) return;
  const float invN = 1.0f / (float)N_NODES;
  float mean = sums[t]*invN;
  float var = fmaxf(sums[64+t]*invN - mean*mean, 0.f);
  float rstd = rsqrtf(var + BN_EPS);
  float gg = g4[t], bb = b4[t];
  int cur = batch[n0]; if((unsigned)cur >= N_GRAPHS) cur = 0;
  float acc = 0.f; int cl = 0;
  for(int n = n0; n < n1; n++){
    int g = batch[n]; if((unsigned)g >= N_GRAPHS) g = 0;
    if(g != cur){
      atomicAdd(&psum[cur*64 + t], acc);
      if(t == 0) atomicAdd(&pcnt[cur], (float)cl);
      acc = 0.f; cl = 0; cur = g;
    }
    float y = (sane(h[(size_t)n*64 + t])-mean)*rstd*gg + bb;
    acc += fmaxf(y, 0.f);
    cl++;
  }
  atomicAdd(&psum[cur*64 + t], acc);
  if(t == 0) atomicAdd(&pcnt[cur], (float)cl);
}

// ---------------- head MLPs + output ----------------
__device__ __forceinline__ void stO(void* o, size_t i, float v, int m){
  if(m) ((float*)o)[i] = v; else ((bf16*)o)[i] = f2b(v);
}

__global__ __launch_bounds__(128) void k_head(
    const float* __restrict__ psum, const float* __restrict__ pcnt,
    const float* __restrict__ exf,
    const float* __restrict__ Wex1, const float* __restrict__ bex1,
    const float* __restrict__ Wex2, const float* __restrict__ bex2,
    const float* __restrict__ Wc1, const float* __restrict__ bc1,
    const float* __restrict__ Wc2, const float* __restrict__ bc2,
    const void* __restrict__ xdet, void* __restrict__ dout){
  int m0 = detect_mode_block(xdet);
  int g = blockIdx.x; int t = threadIdx.x;
  __shared__ float ci[128];
  __shared__ float e1[64];
  __shared__ float comb[128];
  __shared__ float red[128];
  if(t < 64){
    float c = fmaxf(pcnt[g], 1.f);
    float xp = sane(psum[g*64 + t]) / c;
    ci[t] = xp;
    stO(dout, 256 + (size_t)g*64 + t, xp, m0);
  } else {
    int j = t - 64;
    float s = bex1[j];
    for(int k=0;k<32;k++) s += exf[g*32 + k] * Wex1[k*64 + j];
    e1[j] = fmaxf(s, 0.f);
  }
  __syncthreads();
  if(t >= 64){
    int j = t - 64;
    float s = bex2[j];
    for(int k=0;k<64;k++) s += e1[k] * Wex2[k*64 + j];
    ci[64 + j] = fmaxf(s, 0.f);
  }
  __syncthreads();
  {
    float s = bc1[t];
    for(int k=0;k<128;k++) s += ci[k] * Wc1[k*128 + t];
    s = fmaxf(s, 0.f);
    comb[t] = s;
    stO(dout, 256 + 16384 + (size_t)g*128 + t, s, m0);
  }
  __syncthreads();
  red[t] = comb[t] * Wc2[t];
  __syncthreads();
  for(int o=64;o>0;o>>=1){ if(t<o) red[t]+=red[t+o]; __syncthreads(); }
  if(t==0) stO(dout, g, red[0] + bc2[0], m0);
}

// ---------------- launch ----------------
extern "C" void kernel_launch(void* const* d_in, const int* in_sizes, int n_in,
                              void* d_out, int out_size, void* d_ws, size_t ws_size,
                              hipStream_t stream){
  const void* x    = d_in[0];
  const void* ea   = d_in[1];
  const int* ei    = (const int*)d_in[3];
  const int* batch = (const int*)d_in[4];
  const int* src = ei;
  const int* dst = ei + N_EDGES;

  char* base = (char*)d_ws;
  size_t off = 0;
  auto alloc = [&](size_t bytes) -> void* {
    void* r = base + off;
    off += (bytes + 255) & ~(size_t)255;
    return r;
  };
  int*   cnt    = (int*)  alloc((size_t)N_NODES*4);
  int*   fill   = (int*)  alloc((size_t)N_NODES*4);
  float* bnstat = (float*)alloc(4096);
  float* pool   = (float*)alloc((size_t)(N_GRAPHS*64 + N_GRAPHS)*4);
  size_t zbytes = off;
  int*   rp      = (int*)  alloc((size_t)(N_NODES+1)*4);
  int*   bsum    = (int*)  alloc(256*4);
  int*   bofs    = (int*)  alloc(256*4);
  int4*  epk     = (int4*) alloc((size_t)N_EDGES*16);
  float* dinv    = (float*)alloc((size_t)N_NODES*4);
  float* w_e     = (float*)alloc(64*4);
  float* als4    = (float*)alloc((size_t)N_NODES*4*4);
  float* ald4    = (float*)alloc((size_t)N_NODES*4*4);
  float* wbank   = (float*)alloc(80000*4);
  bf16*  xb      = (bf16*) alloc((size_t)N_NODES*64*2);
  bf16*  hp      = (bf16*) alloc((size_t)N_NODES*256*2);
  float* out1    = (float*)alloc((size_t)N_NODES*256*4);

  float* out2 = out1;
  float* out3 = out1 + (size_t)N_NODES*64;
  float* out4 = out1 + (size_t)N_NODES*128;
  float* bn1 = bnstat;
  float* bn2 = bnstat + 512;
  float* bn3 = bnstat + 640;
  float* bn4 = bnstat + 768;
  float* psum = pool;
  float* pcnt = pool + N_GRAPHS*64;

  const int segidx[NSEG] = {2, 5,6,7,8,9,10,11,12, 13,14,15,16,17,18,19,20,
                            21,22,23,24, 25,26,27,28, 29,30,31,32, 33,34,35,36};
  const int segn[NSEG] = {8192, 16384,256,256,2048,256,256,256,256,
                          16384,64,64,512,64,64,64,64,
                          4096,64,64,64, 4096,64,64,64,
                          2048,64,4096,64, 16384,128,128,1};
  Bank bk;
  int offs[NSEG]; int acc0 = 0;
  for(int i=0;i<NSEG;i++){ bk.p[i]=d_in[segidx[i]]; bk.n[i]=segn[i]; bk.off[i]=acc0; offs[i]=acc0; acc0+=segn[i]; }
  const float* f_exf = wbank + offs[0];
  const float* fW1 = wbank+offs[1]; const float* fas1 = wbank+offs[2]; const float* fad1 = wbank+offs[3];
  const float* fWe1= wbank+offs[4]; const float* fae1 = wbank+offs[5]; const float* fb1  = wbank+offs[6];
  const float* fg1 = wbank+offs[7]; const float* fbe1 = wbank+offs[8];
  const float* fW2 = wbank+offs[9]; const float* fas2 = wbank+offs[10]; const float* fad2 = wbank+offs[11];
  const float* fWe2= wbank+offs[12]; const float* fae2 = wbank+offs[13]; const float* fb2 = wbank+offs[14];
  const float* fg2 = wbank+offs[15]; const float* fbe2 = wbank+offs[16];
  const float* fWg1= wbank+offs[17]; const float* fbg1 = wbank+offs[18]; const float* fg3 = wbank+offs[19];
  const float* fbe3= wbank+offs[20];
  const float* fWg2= wbank+offs[21]; const float* fbg2 = wbank+offs[22]; const float* fg4 = wbank+offs[23];
  const float* fbe4= wbank+offs[24];
  const float* fWex1=wbank+offs[25]; const float* fbex1= wbank+offs[26];
  const float* fWex2=wbank+offs[27]; const float* fbex2= wbank+offs[28];
  const float* fWc1= wbank+offs[29]; const float* fbc1 = wbank+offs[30];
  const float* fWc2= wbank+offs[31]; const float* fbc2 = wbank+offs[32];

  const int nbN  = (N_NODES + 255)/256;
  const int nbE  = (N_EDGES + 255)/256;
  const int nbT  = (N_NODES + 63)/64;

  hipMemsetAsync(d_ws, 0, zbytes, stream);
  {
    dim3 g((16384+255)/256, NSEG);
    k_convert<<<g,256,0,stream>>>(bk, x, wbank);
  }
  k_cvt_x<<<(N_NODES*16+255)/256,256,0,stream>>>(x, xb);
  k_we<<<1,64,0,stream>>>(fWe1, fae1, fWe2, fae2, w_e);
  k_count<<<nbE,256,0,stream>>>(dst, cnt);
  k_blocksum<<<nbN,256,0,stream>>>(cnt, bsum);
  k_scan_bsum<<<1,256,0,stream>>>(bsum, bofs, nbN);
  k_scan_write<<<nbN,256,0,stream>>>(cnt, bofs, rp, dinv);
  k_fill<<<nbE,256,0,stream>>>(src, dst, rp, fill, ea, x, w_e, epk);

  // GAT layer 1 (4 heads via grid.y)
  {
    dim3 g(nbT, 4);
    k_gemmA<<<g,256,0,stream>>>(xb, fW1, hp, N_NODES);
  }
  k_al4<<<(N_NODES*4+255)/256,256,0,stream>>>(hp, fas1, fad1, als4, ald4);
  k_gat_agg4<<<N_NODES,64,0,stream>>>(rp, epk, hp, als4, ald4, fb1, out1);
  k_colstats<256><<<(N_NODES+127)/128,256,0,stream>>>(out1, bn1);

  // GAT layer 2 (1 head) — BN1+ReLU fused into A-staging
  k_gemmB<256,true><<<nbT,256,0,stream>>>(out1, fW2, hp, N_NODES, bn1, fg1, fbe1);
  k_al1<<<nbN,256,0,stream>>>(hp, fas2, fad2, als4, ald4);
  k_gat_agg1e<<<N_NODES,64,0,stream>>>(rp, epk, hp, als4, ald4, fb2, out2);
  k_colstats<64><<<(N_NODES+127)/128,256,0,stream>>>(out2, bn2);

  // GCN layer 1 — BN2+ReLU fused
  k_gemmB<64,true><<<nbT,256,0,stream>>>(out2, fWg1, hp, N_NODES, bn2, fg2, fbe2);
  k_gcn_agg<<<N_NODES,64,0,stream>>>(rp, epk, dinv, hp, fbg1, out3);
  k_colstats<64><<<(N_NODES+127)/128,256,0,stream>>>(out3, bn3);

  // GCN layer 2 — BN3+ReLU fused
  k_gemmB<64,true><<<nbT,256,0,stream>>>(out3, fWg2, hp, N_NODES, bn3, fg3, fbe3);
  k_gcn_agg<<<N_NODES,64,0,stream>>>(rp, epk, dinv, hp, fbg2, out4);
  k_colstats<64><<<(N_NODES+127)/128,256,0,stream>>>(out4, bn4);

  // pool (BN4+ReLU fused) + head
  k_pool3<<<nbN,64,0,stream>>>(out4, batch, bn4, fg4, fbe4, psum, pcnt);
  k_head<<<N_GRAPHS,128,0,stream>>>(psum, pcnt, f_exf, fWex1, fbex1, fWex2, fbex2,
                                    fWc1, fbc1, fWc2, fbc2, x, (void*)d_out);
}

// Round 10
// 973.953 us; speedup vs baseline: 1.2219x; 1.0332x over previous
//
#include <hip/hip_runtime.h>
#include <hip/hip_bf16.h>

#define N_NODES 50000
#define N_EDGES 1600000
#define N_GRAPHS 256
#define NEG_SLOPE 0.2f
#define BN_EPS 1e-5f

typedef __hip_bfloat16 bf16;

__device__ __forceinline__ float b2f(bf16 v){ return __bfloat162float(v); }
__device__ __forceinline__ bf16 f2b(float v){ return __float2bfloat16(v); }
__device__ __forceinline__ float us2f(unsigned short u){ return __uint_as_float(((unsigned)u)<<16); }
__device__ __forceinline__ unsigned short f2us(float v){ bf16 b = f2b(v); return *(unsigned short*)&b; }
__device__ __forceinline__ unsigned pk2(float a, float b){ return (unsigned)f2us(a) | ((unsigned)f2us(b)<<16); }
__device__ __forceinline__ float ldF(const void* p, size_t i, int m){
  return m ? ((const float*)p)[i] : b2f(((const bf16*)p)[i]);
}
__device__ __forceinline__ float sane(float v){
  return (v == v && fabsf(v) < 1e30f) ? v : 0.f;
}
__device__ __forceinline__ float sel4(const float v[4], int h){
  float r = v[0];
  r = (h==1) ? v[1] : r;
  r = (h==2) ? v[2] : r;
  r = (h==3) ? v[3] : r;
  return r;
}
// acc[0..7] += w * (8 bf16 packed in uint4)
__device__ __forceinline__ void acc8(float* acc, float w, uint4 u){
  acc[0] += w*us2f((unsigned short)(u.x & 0xffff)); acc[1] += w*us2f((unsigned short)(u.x >> 16));
  acc[2] += w*us2f((unsigned short)(u.y & 0xffff)); acc[3] += w*us2f((unsigned short)(u.y >> 16));
  acc[4] += w*us2f((unsigned short)(u.z & 0xffff)); acc[5] += w*us2f((unsigned short)(u.z >> 16));
  acc[6] += w*us2f((unsigned short)(u.w & 0xffff)); acc[7] += w*us2f((unsigned short)(u.w >> 16));
}
__device__ __forceinline__ void unp8(float* o, uint4 u){
  o[0] = us2f((unsigned short)(u.x & 0xffff)); o[1] = us2f((unsigned short)(u.x >> 16));
  o[2] = us2f((unsigned short)(u.y & 0xffff)); o[3] = us2f((unsigned short)(u.y >> 16));
  o[4] = us2f((unsigned short)(u.z & 0xffff)); o[5] = us2f((unsigned short)(u.z >> 16));
  o[6] = us2f((unsigned short)(u.w & 0xffff)); o[7] = us2f((unsigned short)(u.w >> 16));
}

// block-level dtype detection
__device__ int detect_mode_block(const void* x){
  __shared__ int s_ins;
  if(threadIdx.x == 0) s_ins = 0;
  __syncthreads();
  const unsigned short* u = (const unsigned short*)x;
  int c = 0;
  for(int i = threadIdx.x; i < 1024; i += blockDim.x){
    float v = fabsf(us2f(u[i]));
    if(!(v > 1e-6f && v < 1e4f)) c++;
  }
  if(c) atomicAdd(&s_ins, c);
  __syncthreads();
  return (s_ins > 128) ? 1 : 0;   // 1 => f32
}

// ---------------- weight bank conversion ----------------
#define NSEG 33
struct Bank { const void* p[NSEG]; int n[NSEG]; int off[NSEG]; };

__global__ void k_convert(Bank b, const void* xdet, float* out){
  int m = detect_mode_block(xdet);
  int seg = blockIdx.y;
  int i = blockIdx.x*256 + threadIdx.x;
  if(i < b.n[seg]) out[b.off[seg] + i] = ldF(b.p[seg], i, m);
}

__global__ void k_cvt_x(const void* x, bf16* xb){
  int m = detect_mode_block(x);
  int i4 = blockIdx.x*256 + threadIdx.x;
  if(i4 >= N_NODES*16) return;
  if(m){
    float4 v = ((const float4*)x)[i4];
    ((ushort4*)xb)[i4] = make_ushort4(f2us(v.x), f2us(v.y), f2us(v.z), f2us(v.w));
  } else {
    ((ushort4*)xb)[i4] = ((const ushort4*)x)[i4];
  }
}

__global__ void k_we(const float* __restrict__ We1, const float* __restrict__ ae1,
                     const float* __restrict__ We2, const float* __restrict__ ae2,
                     float* __restrict__ w_e){
  int t = threadIdx.x;
  if(t < 32){
    int h = t >> 3, k = t & 7;
    float s = 0.f;
    for(int d=0;d<64;d++) s += We1[k*256 + h*64 + d] * ae1[h*64 + d];
    w_e[t] = s;
  } else if(t < 40){
    int k = t - 32;
    float s = 0.f;
    for(int d=0;d<64;d++) s += We2[k*64 + d] * ae2[d];
    w_e[t] = s;
  }
}

// ---------------- CSR build ----------------
__global__ void k_count(const int* __restrict__ dst, int* __restrict__ cnt){
  int e = blockIdx.x*256 + threadIdx.x;
  if(e < N_EDGES){
    int d = dst[e]; if((unsigned)d >= N_NODES) d = 0;
    atomicAdd(&cnt[d], 1);
  }
}

__global__ void k_blocksum(const int* __restrict__ cnt, int* __restrict__ bsum){
  __shared__ int s[256];
  int i = blockIdx.x*256 + threadIdx.x;
  s[threadIdx.x] = (i < N_NODES) ? cnt[i] : 0;
  __syncthreads();
  for(int o=128;o>0;o>>=1){ if(threadIdx.x<o) s[threadIdx.x]+=s[threadIdx.x+o]; __syncthreads(); }
  if(threadIdx.x==0) bsum[blockIdx.x]=s[0];
}

__global__ void k_scan_bsum(const int* __restrict__ bsum, int* __restrict__ bofs, int nb){
  __shared__ int s[256];
  int t = threadIdx.x;
  s[t] = (t<nb) ? bsum[t] : 0;
  __syncthreads();
  for(int o=1;o<256;o<<=1){ int v=(t>=o)?s[t-o]:0; __syncthreads(); s[t]+=v; __syncthreads(); }
  bofs[t] = (t==0) ? 0 : s[t-1];
}

__global__ void k_scan_write(const int* __restrict__ cnt, const int* __restrict__ bofs,
                             int* __restrict__ rp, float* __restrict__ dinv){
  __shared__ int s[256];
  int t = threadIdx.x; int i = blockIdx.x*256 + t;
  int v = (i<N_NODES) ? cnt[i] : 0;
  s[t]=v; __syncthreads();
  for(int o=1;o<256;o<<=1){ int a=(t>=o)?s[t-o]:0; __syncthreads(); s[t]+=a; __syncthreads(); }
  if(i<N_NODES){
    rp[i+1] = s[t] + bofs[blockIdx.x];
    dinv[i] = rsqrtf((float)v + 1.f);
  }
  if(i==0) rp[0]=0;
}

// fill CSR: packed 16B record per slot = {src, edot4[4] bf16, edot1 bf16}
__global__ void k_fill(const int* __restrict__ src, const int* __restrict__ dst,
                       const int* __restrict__ rp, int* __restrict__ fill,
                       const void* __restrict__ ea, const void* __restrict__ xdet,
                       const float* __restrict__ w_e,
                       int4* __restrict__ epk){
  int m = detect_mode_block(xdet);
  int e = blockIdx.x*256 + threadIdx.x;
  if(e >= N_EDGES) return;
  int d = dst[e]; if((unsigned)d >= N_NODES) d = 0;
  int p = atomicAdd(&fill[d], 1);
  int slot = rp[d] + p;
  if((unsigned)slot >= N_EDGES) return;
  int sv = src[e]; if((unsigned)sv >= N_NODES) sv = 0;
  float a[8];
  if(m){
    const float* eaf = (const float*)ea;
    float4 lo = *(const float4*)&eaf[(size_t)e*8];
    float4 hi = *(const float4*)&eaf[(size_t)e*8 + 4];
    a[0]=lo.x; a[1]=lo.y; a[2]=lo.z; a[3]=lo.w;
    a[4]=hi.x; a[5]=hi.y; a[6]=hi.z; a[7]=hi.w;
  } else {
    #pragma unroll
    for(int k=0;k<8;k++) a[k] = b2f(((const bf16*)ea)[(size_t)e*8 + k]);
  }
  unsigned d4[4];
  #pragma unroll
  for(int h=0;h<4;h++){
    float s = 0.f;
    #pragma unroll
    for(int k=0;k<8;k++) s += a[k]*w_e[h*8+k];
    d4[h] = f2us(s);
  }
  float s1 = 0.f;
  #pragma unroll
  for(int k=0;k<8;k++) s1 += a[k]*w_e[32+k];
  int4 pk;
  pk.x = sv;
  pk.y = (int)(d4[0] | (d4[1] << 16));
  pk.z = (int)(d4[2] | (d4[3] << 16));
  pk.w = (int)(unsigned)f2us(s1);
  epk[slot] = pk;
}

// ---------------- GEMM layer 1 ----------------
__global__ __launch_bounds__(256, 3) void k_gemmA(
    const bf16* __restrict__ xb, const float* __restrict__ W1,
    bf16* __restrict__ hp, int M)
{
  __shared__ float As[64][68];
  __shared__ float Ws[64][64];
  const int tid = threadIdx.x;
  const int bm  = blockIdx.x * 64;
  const int h   = blockIdx.y;
  const int tx  = tid & 15;
  const int ty  = tid >> 4;
  float acc[4][4] = {};

  #pragma unroll
  for(int f = tid; f < 1024; f += 256){
    int r = f >> 4, kq = f & 15;
    int row = bm + r;
    float4 v = make_float4(0.f,0.f,0.f,0.f);
    if(row < M){
      ushort4 u = *(const ushort4*)&xb[(size_t)row*64 + 4*kq];
      v = make_float4(us2f(u.x), us2f(u.y), us2f(u.z), us2f(u.w));
    }
    *(float4*)&As[r][4*kq] = v;
  }
  #pragma unroll
  for(int g = tid; g < 1024; g += 256){
    int kr = g >> 4, jq = g & 15;
    *(float4*)&Ws[kr][4*jq] = *(const float4*)&W1[(size_t)kr*256 + h*64 + 4*jq];
  }
  __syncthreads();
  #pragma unroll 2
  for(int k = 0; k < 64; k += 4){
    float4 av[4], wv[4];
    #pragma unroll
    for(int r=0;r<4;r++) av[r] = *(const float4*)&As[4*ty + r][k];
    #pragma unroll
    for(int kk=0;kk<4;kk++) wv[kk] = *(const float4*)&Ws[k + kk][4*tx];
    #pragma unroll
    for(int r=0;r<4;r++){
      const float a0=av[r].x, a1=av[r].y, a2=av[r].z, a3=av[r].w;
      acc[r][0] += a0*wv[0].x + a1*wv[1].x + a2*wv[2].x + a3*wv[3].x;
      acc[r][1] += a0*wv[0].y + a1*wv[1].y + a2*wv[2].y + a3*wv[3].y;
      acc[r][2] += a0*wv[0].z + a1*wv[1].z + a2*wv[2].z + a3*wv[3].z;
      acc[r][3] += a0*wv[0].w + a1*wv[1].w + a2*wv[2].w + a3*wv[3].w;
    }
  }
  #pragma unroll
  for(int r=0;r<4;r++){
    int row = bm + 4*ty + r;
    if(row < M){
      ushort4 u = make_ushort4(f2us(acc[r][0]), f2us(acc[r][1]), f2us(acc[r][2]), f2us(acc[r][3]));
      *(ushort4*)&hp[(size_t)row*256 + h*64 + 4*tx] = u;
    }
  }
}

// ---------------- GEMM layers 2-4: bf16 A [N,KIN] + fused BN-ReLU -> bf16 C [N,64] ----------------
template<int KIN>
__global__ __launch_bounds__(256, 3) void k_gemmB(
    const bf16* __restrict__ A, const float* __restrict__ W,
    bf16* __restrict__ C, int M,
    const float* __restrict__ bnsums, const float* __restrict__ bng, const float* __restrict__ bnb)
{
  __shared__ float As[64][68];
  __shared__ float Ws[64][64];
  const int tid = threadIdx.x;
  const int bm  = blockIdx.x * 64;
  const int tx  = tid & 15;
  const int ty  = tid >> 4;
  const float invN = 1.0f / (float)N_NODES;
  float acc[4][4] = {};

  for(int k0 = 0; k0 < KIN; k0 += 64){
    #pragma unroll
    for(int f = tid; f < 1024; f += 256){
      int r = f >> 4, kq = f & 15;
      int row = bm + r;
      float vv[4] = {0.f,0.f,0.f,0.f};
      if(row < M){
        ushort4 u = *(const ushort4*)&A[(size_t)row*KIN + k0 + 4*kq];
        vv[0]=us2f(u.x); vv[1]=us2f(u.y); vv[2]=us2f(u.z); vv[3]=us2f(u.w);
      }
      int c = k0 + 4*kq;
      #pragma unroll
      for(int j=0;j<4;j++){
        int cc = c + j;
        float mean = bnsums[cc]*invN;
        float var = fmaxf(bnsums[KIN+cc]*invN - mean*mean, 0.f);
        float y = (sane(vv[j])-mean)*rsqrtf(var + BN_EPS)*bng[cc] + bnb[cc];
        vv[j] = fmaxf(y, 0.f);
      }
      *(float4*)&As[r][4*kq] = make_float4(vv[0], vv[1], vv[2], vv[3]);
    }
    #pragma unroll
    for(int g = tid; g < 1024; g += 256){
      int kr = g >> 4, jq = g & 15;
      *(float4*)&Ws[kr][4*jq] = *(const float4*)&W[(size_t)(k0+kr)*64 + 4*jq];
    }
    __syncthreads();
    #pragma unroll 2
    for(int k = 0; k < 64; k += 4){
      float4 av[4], wv[4];
      #pragma unroll
      for(int r=0;r<4;r++) av[r] = *(const float4*)&As[4*ty + r][k];
      #pragma unroll
      for(int kk=0;kk<4;kk++) wv[kk] = *(const float4*)&Ws[k + kk][4*tx];
      #pragma unroll
      for(int r=0;r<4;r++){
        const float a0=av[r].x, a1=av[r].y, a2=av[r].z, a3=av[r].w;
        acc[r][0] += a0*wv[0].x + a1*wv[1].x + a2*wv[2].x + a3*wv[3].x;
        acc[r][1] += a0*wv[0].y + a1*wv[1].y + a2*wv[2].y + a3*wv[3].y;
        acc[r][2] += a0*wv[0].z + a1*wv[1].z + a2*wv[2].z + a3*wv[3].z;
        acc[r][3] += a0*wv[0].w + a1*wv[1].w + a2*wv[2].w + a3*wv[3].w;
      }
    }
    __syncthreads();
  }
  #pragma unroll
  for(int r=0;r<4;r++){
    int row = bm + 4*ty + r;
    if(row < M){
      ushort4 u = make_ushort4(f2us(acc[r][0]), f2us(acc[r][1]), f2us(acc[r][2]), f2us(acc[r][3]));
      *(ushort4*)&C[(size_t)row*64 + 4*tx] = u;
    }
  }
}

// ---------------- alpha dots ----------------
__global__ void k_al4(const bf16* __restrict__ hp, const float* __restrict__ asrc,
                      const float* __restrict__ adst,
                      float* __restrict__ als4, float* __restrict__ ald4){
  int idx = blockIdx.x*256 + threadIdx.x;
  if(idx >= N_NODES*4) return;
  int n = idx >> 2, h = idx & 3;
  const unsigned short* row = (const unsigned short*)hp + (size_t)n*256 + h*64;
  float ss=0.f, sd=0.f;
  #pragma unroll
  for(int q=0;q<16;q++){
    ushort4 u = *(const ushort4*)&row[4*q];
    float4 a_s = *(const float4*)&asrc[h*64 + 4*q];
    float4 a_d = *(const float4*)&adst[h*64 + 4*q];
    float v0=us2f(u.x), v1=us2f(u.y), v2=us2f(u.z), v3=us2f(u.w);
    ss += v0*a_s.x + v1*a_s.y + v2*a_s.z + v3*a_s.w;
    sd += v0*a_d.x + v1*a_d.y + v2*a_d.z + v3*a_d.w;
  }
  als4[idx]=ss; ald4[idx]=sd;
}

__global__ void k_al1(const bf16* __restrict__ hp, const float* __restrict__ asrc,
                      const float* __restrict__ adst,
                      float* __restrict__ als, float* __restrict__ ald){
  int n = blockIdx.x*256 + threadIdx.x;
  if(n >= N_NODES) return;
  const unsigned short* row = (const unsigned short*)hp + (size_t)n*64;
  float ss=0.f, sd=0.f;
  #pragma unroll
  for(int q=0;q<16;q++){
    ushort4 u = *(const ushort4*)&row[4*q];
    float4 a_s = *(const float4*)&asrc[4*q];
    float4 a_d = *(const float4*)&adst[4*q];
    float v0=us2f(u.x), v1=us2f(u.y), v2=us2f(u.z), v3=us2f(u.w);
    ss += v0*a_s.x + v1*a_s.y + v2*a_s.z + v3*a_s.w;
    sd += v0*a_d.x + v1*a_d.y + v2*a_d.z + v3*a_d.w;
  }
  als[n]=ss; ald[n]=sd;
}

// ---------------- fused 4-head GAT aggregate: 2 edges in flight, 16B row loads ----------------
// half-wave eh = t>>5 takes edge parity; c8 = t&31 owns cols 8*c8..8*c8+7 (head = c8>>3)
__global__ __launch_bounds__(64) void k_gat_agg4(
    const int* __restrict__ rp, const int4* __restrict__ epk,
    const bf16* __restrict__ hp,                 // [N,256]
    const float* __restrict__ als4, const float* __restrict__ ald4,
    const float* __restrict__ bias256, bf16* __restrict__ out1){
  int n = blockIdx.x; int t = threadIdx.x;
  int eh = t >> 5, c8 = t & 31;
  int head = c8 >> 3;
  __shared__ int   ssrc[64];
  __shared__ float swt[64][4];
  int s0 = rp[n], e0 = rp[n+1];
  if((unsigned)s0 > N_EDGES){ s0=0; e0=0; }
  if(e0 < s0 || (unsigned)e0 > N_EDGES) e0 = s0;
  float4 aldv = *(const float4*)&ald4[n*4];
  float4 alsvn = *(const float4*)&als4[n*4];
  float wsum[4] = {0.f,0.f,0.f,0.f};
  float dsum[4] = {0.f,0.f,0.f,0.f};
  float acc[8]  = {0.f,0.f,0.f,0.f,0.f,0.f,0.f,0.f};
  const unsigned short* hpu = (const unsigned short*)hp;

  for(int base = s0; base < e0; base += 64){
    int m = min(64, e0 - base);
    if(t < m){
      int4 pk = epk[base+t];
      int sn = pk.x; if((unsigned)sn >= N_NODES) sn = 0;
      ssrc[t] = sn;
      float edf[4] = {us2f((unsigned short)(pk.y & 0xffff)), us2f((unsigned short)((unsigned)pk.y >> 16)),
                      us2f((unsigned short)(pk.z & 0xffff)), us2f((unsigned short)((unsigned)pk.z >> 16))};
      float4 alss = *(const float4*)&als4[sn*4];
      float alssv[4] = {alss.x, alss.y, alss.z, alss.w};
      float aldvv[4] = {aldv.x, aldv.y, aldv.z, aldv.w};
      float w4[4];
      #pragma unroll
      for(int h=0;h<4;h++){
        float sc = alssv[h] + aldvv[h] + edf[h];
        sc = sc > 0.f ? sc : NEG_SLOPE*sc;
        sc = fminf(sc, 30.f);
        float w = expf(sc);
        w4[h] = w;
        wsum[h] += w; dsum[h] += edf[h];
      }
      *(float4*)&swt[t][0] = make_float4(w4[0], w4[1], w4[2], w4[3]);
    }
    __syncthreads();
    #pragma unroll 4
    for(int i=0;i<m;i+=2){
      int j = i + eh;
      if(j < m){
        int row = ssrc[j];
        float w = swt[j][head];
        uint4 u = *(const uint4*)&hpu[(size_t)row*256 + 8*c8];
        acc8(acc, w, u);
      }
    }
    __syncthreads();
  }
  // butterfly wsum/dsum across 64 lanes; merge edge-parity halves of acc
  #pragma unroll
  for(int o=1;o<64;o<<=1){
    #pragma unroll
    for(int h=0;h<4;h++){
      wsum[h] += __shfl_xor(wsum[h], o);
      dsum[h] += __shfl_xor(dsum[h], o);
    }
  }
  #pragma unroll
  for(int q=0;q<8;q++) acc[q] += __shfl_xor(acc[q], 32);
  if(eh == 0){
    float alsnv[4] = {alsvn.x, alsvn.y, alsvn.z, alsvn.w};
    float aldnv[4] = {aldv.x, aldv.y, aldv.z, aldv.w};
    float sEh = sel4(wsum, head), sDh = sel4(dsum, head);
    float deg = (float)(e0 - s0);
    float sdot = deg > 0.f ? sDh/deg : 0.f;
    float sc = sel4(alsnv, head) + sel4(aldnv, head) + sdot;
    sc = sc > 0.f ? sc : NEG_SLOPE*sc;
    sc = fminf(sc, 30.f);
    float wself = expf(sc);
    float self[8];
    unp8(self, *(const uint4*)&hpu[(size_t)n*256 + 8*c8]);
    float4 b0 = *(const float4*)&bias256[8*c8];
    float4 b1 = *(const float4*)&bias256[8*c8 + 4];
    float bi[8] = {b0.x,b0.y,b0.z,b0.w,b1.x,b1.y,b1.z,b1.w};
    float inv = 1.f/(sEh + wself);
    float o8[8];
    #pragma unroll
    for(int q=0;q<8;q++) o8[q] = (acc[q] + wself*self[q])*inv + bi[q];
    uint4 st;
    st.x = pk2(o8[0],o8[1]); st.y = pk2(o8[2],o8[3]);
    st.z = pk2(o8[4],o8[5]); st.w = pk2(o8[6],o8[7]);
    *(uint4*)&((unsigned short*)out1)[(size_t)n*256 + 8*c8] = st;
  }
}

// ---------------- single-head GAT aggregate: 8 edges in flight, 16B loads ----------------
__global__ __launch_bounds__(64) void k_gat_agg1e(
    const int* __restrict__ rp, const int4* __restrict__ epk,
    const bf16* __restrict__ hp,                 // [N,64]
    const float* __restrict__ als, const float* __restrict__ ald,
    const float* __restrict__ bias64, bf16* __restrict__ out){
  int n = blockIdx.x; int t = threadIdx.x;
  int eg = t >> 3, c8 = t & 7;
  __shared__ float sw[64];
  __shared__ int   ssrc[64];
  int s0 = rp[n], e0 = rp[n+1];
  if((unsigned)s0 > N_EDGES){ s0=0; e0=0; }
  if(e0 < s0 || (unsigned)e0 > N_EDGES) e0 = s0;
  float aldn = ald[n];
  float wsum_l = 0.f, dsum_l = 0.f;
  float acc[8] = {0.f,0.f,0.f,0.f,0.f,0.f,0.f,0.f};
  const unsigned short* hpu = (const unsigned short*)hp;
  for(int base = s0; base < e0; base += 64){
    int m = min(64, e0 - base);
    if(t < m){
      int4 pk = epk[base+t];
      int sn = pk.x; if((unsigned)sn >= N_NODES) sn = 0;
      ssrc[t] = sn;
      float ed = us2f((unsigned short)(pk.w & 0xffff));
      float sc = als[sn] + aldn + ed;
      sc = sc > 0.f ? sc : NEG_SLOPE*sc;
      sc = fminf(sc, 30.f);
      float w = expf(sc);
      sw[t] = w;
      wsum_l += w; dsum_l += ed;
    }
    __syncthreads();
    #pragma unroll 2
    for(int i=0;i<m;i+=8){
      int j = i + eg;
      if(j < m){
        int row = ssrc[j];
        float w = sw[j];
        uint4 u = *(const uint4*)&hpu[(size_t)row*64 + 8*c8];
        acc8(acc, w, u);
      }
    }
    __syncthreads();
  }
  #pragma unroll
  for(int o=1;o<64;o<<=1){ wsum_l += __shfl_xor(wsum_l, o); dsum_l += __shfl_xor(dsum_l, o); }
  #pragma unroll
  for(int q=0;q<8;q++){
    acc[q] += __shfl_xor(acc[q], 8);
    acc[q] += __shfl_xor(acc[q], 16);
    acc[q] += __shfl_xor(acc[q], 32);
  }
  if(t < 8){
    float deg = (float)(e0 - s0);
    float sdot = deg > 0.f ? dsum_l/deg : 0.f;
    float sc = als[n] + aldn + sdot;
    sc = sc > 0.f ? sc : NEG_SLOPE*sc;
    sc = fminf(sc, 30.f);
    float wself = expf(sc);
    float self[8];
    unp8(self, *(const uint4*)&hpu[(size_t)n*64 + 8*t]);
    float4 b0 = *(const float4*)&bias64[8*t];
    float4 b1 = *(const float4*)&bias64[8*t + 4];
    float bi[8] = {b0.x,b0.y,b0.z,b0.w,b1.x,b1.y,b1.z,b1.w};
    float inv = 1.f/(wsum_l + wself);
    float o8[8];
    #pragma unroll
    for(int q=0;q<8;q++) o8[q] = (acc[q] + wself*self[q])*inv + bi[q];
    uint4 st;
    st.x = pk2(o8[0],o8[1]); st.y = pk2(o8[2],o8[3]);
    st.z = pk2(o8[4],o8[5]); st.w = pk2(o8[6],o8[7]);
    *(uint4*)&((unsigned short*)out)[(size_t)n*64 + 8*t] = st;
  }
}

// ---------------- GCN aggregate: 8 edges in flight, 16B loads ----------------
__global__ __launch_bounds__(64) void k_gcn_agg(
    const int* __restrict__ rp, const int4* __restrict__ epk,
    const float* __restrict__ dinv, const bf16* __restrict__ gp,
    const float* __restrict__ bias, bf16* __restrict__ out){
  int n = blockIdx.x; int t = threadIdx.x;
  int eg = t >> 3, c8 = t & 7;
  __shared__ float sw[64];
  __shared__ int   ssrc[64];
  int s0 = rp[n], e0 = rp[n+1];
  if((unsigned)s0 > N_EDGES){ s0=0; e0=0; }
  if(e0 < s0 || (unsigned)e0 > N_EDGES) e0 = s0;
  float dn = dinv[n];
  float acc[8] = {0.f,0.f,0.f,0.f,0.f,0.f,0.f,0.f};
  const unsigned short* gpu = (const unsigned short*)gp;
  for(int base = s0; base < e0; base += 64){
    int m = min(64, e0 - base);
    if(t < m){
      int sn = epk[base+t].x; if((unsigned)sn >= N_NODES) sn = 0;
      ssrc[t]=sn; sw[t]=dinv[sn];
    }
    __syncthreads();
    #pragma unroll 2
    for(int i=0;i<m;i+=8){
      int j = i + eg;
      if(j < m){
        int row = ssrc[j];
        float w = sw[j];
        uint4 u = *(const uint4*)&gpu[(size_t)row*64 + 8*c8];
        acc8(acc, w, u);
      }
    }
    __syncthreads();
  }
  #pragma unroll
  for(int q=0;q<8;q++){
    acc[q] += __shfl_xor(acc[q], 8);
    acc[q] += __shfl_xor(acc[q], 16);
    acc[q] += __shfl_xor(acc[q], 32);
  }
  if(t < 8){
    float self[8];
    unp8(self, *(const uint4*)&gpu[(size_t)n*64 + 8*t]);
    float4 b0 = *(const float4*)&bias[8*t];
    float4 b1 = *(const float4*)&bias[8*t + 4];
    float bi[8] = {b0.x,b0.y,b0.z,b0.w,b1.x,b1.y,b1.z,b1.w};
    float o8[8];
    #pragma unroll
    for(int q=0;q<8;q++) o8[q] = dn*(acc[q] + dn*self[q]) + bi[q];
    uint4 st;
    st.x = pk2(o8[0],o8[1]); st.y = pk2(o8[2],o8[3]);
    st.z = pk2(o8[4],o8[5]); st.w = pk2(o8[6],o8[7]);
    *(uint4*)&((unsigned short*)out)[(size_t)n*64 + 8*t] = st;
  }
}

// ---------------- BN stats (bf16 input) ----------------
template<int C>
__global__ void k_colstats(const bf16* __restrict__ X, float* __restrict__ sums){
  constexpr int RPB = 128;
  constexpr int RSTEP = 256 / C;
  int c = threadIdx.x % C;
  int r0 = threadIdx.x / C;
  int rbeg = blockIdx.x * RPB;
  int rend = min(N_NODES, rbeg + RPB);
  const unsigned short* Xu = (const unsigned short*)X;
  float s = 0.f, q = 0.f;
  for(int r = rbeg + r0; r < rend; r += RSTEP){
    float v = sane(us2f(Xu[(size_t)r*C + c]));
    s += v; q += v*v;
  }
  atomicAdd(&sums[c], s);
  atomicAdd(&sums[C + c], q);
}

// ---------------- mean pool with fused BN+ReLU (bf16 input) ----------------
__global__ __launch_bounds__(64) void k_pool3(
    const bf16* __restrict__ h, const int* __restrict__ batch,
    const float* __restrict__ sums, const float* __restrict__ g4,
    const float* __restrict__ b4,
    float* __restrict__ psum, float* __restrict__ pcnt){
  int t = threadIdx.x;
  int n0 = blockIdx.x * 256;
  int n1 = min(N_NODES, n0 + 256);
  if(n0 >= n1) return;
  const float invN = 1.0f / (float)N_NODES;
  float mean = sums[t]*invN;
  float var = fmaxf(sums[64+t]*invN - mean*mean, 0.f);
  float rstd = rsqrtf(var + BN_EPS);
  float gg = g4[t], bb = b4[t];
  const unsigned short* hu = (const unsigned short*)h;
  int cur = batch[n0]; if((unsigned)cur >= N_GRAPHS) cur = 0;
  float acc = 0.f; int cl = 0;
  for(int n = n0; n < n1; n++){
    int g = batch[n]; if((unsigned)g >= N_GRAPHS) g = 0;
    if(g != cur){
      atomicAdd(&psum[cur*64 + t], acc);
      if(t == 0) atomicAdd(&pcnt[cur], (float)cl);
      acc = 0.f; cl = 0; cur = g;
    }
    float y = (sane(us2f(hu[(size_t)n*64 + t]))-mean)*rstd*gg + bb;
    acc += fmaxf(y, 0.f);
    cl++;
  }
  atomicAdd(&psum[cur*64 + t], acc);
  if(t == 0) atomicAdd(&pcnt[cur], (float)cl);
}

// ---------------- head MLPs + output ----------------
__device__ __forceinline__ void stO(void* o, size_t i, float v, int m){
  if(m) ((float*)o)[i] = v; else ((bf16*)o)[i] = f2b(v);
}

__global__ __launch_bounds__(128) void k_head(
    const float* __restrict__ psum, const float* __restrict__ pcnt,
    const float* __restrict__ exf,
    const float* __restrict__ Wex1, const float* __restrict__ bex1,
    const float* __restrict__ Wex2, const float* __restrict__ bex2,
    const float* __restrict__ Wc1, const float* __restrict__ bc1,
    const float* __restrict__ Wc2, const float* __restrict__ bc2,
    const void* __restrict__ xdet, void* __restrict__ dout){
  int m0 = detect_mode_block(xdet);
  int g = blockIdx.x; int t = threadIdx.x;
  __shared__ float ci[128];
  __shared__ float e1[64];
  __shared__ float comb[128];
  __shared__ float red[128];
  if(t < 64){
    float c = fmaxf(pcnt[g], 1.f);
    float xp = sane(psum[g*64 + t]) / c;
    ci[t] = xp;
    stO(dout, 256 + (size_t)g*64 + t, xp, m0);
  } else {
    int j = t - 64;
    float s = bex1[j];
    for(int k=0;k<32;k++) s += exf[g*32 + k] * Wex1[k*64 + j];
    e1[j] = fmaxf(s, 0.f);
  }
  __syncthreads();
  if(t >= 64){
    int j = t - 64;
    float s = bex2[j];
    for(int k=0;k<64;k++) s += e1[k] * Wex2[k*64 + j];
    ci[64 + j] = fmaxf(s, 0.f);
  }
  __syncthreads();
  {
    float s = bc1[t];
    for(int k=0;k<128;k++) s += ci[k] * Wc1[k*128 + t];
    s = fmaxf(s, 0.f);
    comb[t] = s;
    stO(dout, 256 + 16384 + (size_t)g*128 + t, s, m0);
  }
  __syncthreads();
  red[t] = comb[t] * Wc2[t];
  __syncthreads();
  for(int o=64;o>0;o>>=1){ if(t<o) red[t]+=red[t+o]; __syncthreads(); }
  if(t==0) stO(dout, g, red[0] + bc2[0], m0);
}

// ---------------- launch ----------------
extern "C" void kernel_launch(void* const* d_in, const int* in_sizes, int n_in,
                              void* d_out, int out_size, void* d_ws, size_t ws_size,
                              hipStream_t stream){
  const void* x    = d_in[0];
  const void* ea   = d_in[1];
  const int* ei    = (const int*)d_in[3];
  const int* batch = (const int*)d_in[4];
  const int* src = ei;
  const int* dst = ei + N_EDGES;

  char* base = (char*)d_ws;
  size_t off = 0;
  auto alloc = [&](size_t bytes) -> void* {
    void* r = base + off;
    off += (bytes + 255) & ~(size_t)255;
    return r;
  };
  int*   cnt    = (int*)  alloc((size_t)N_NODES*4);
  int*   fill   = (int*)  alloc((size_t)N_NODES*4);
  float* bnstat = (float*)alloc(4096);
  float* pool   = (float*)alloc((size_t)(N_GRAPHS*64 + N_GRAPHS)*4);
  size_t zbytes = off;
  int*   rp      = (int*)  alloc((size_t)(N_NODES+1)*4);
  int*   bsum    = (int*)  alloc(256*4);
  int*   bofs    = (int*)  alloc(256*4);
  int4*  epk     = (int4*) alloc((size_t)N_EDGES*16);
  float* dinv    = (float*)alloc((size_t)N_NODES*4);
  float* w_e     = (float*)alloc(64*4);
  float* als4    = (float*)alloc((size_t)N_NODES*4*4);
  float* ald4    = (float*)alloc((size_t)N_NODES*4*4);
  float* wbank   = (float*)alloc(80000*4);
  bf16*  xb      = (bf16*) alloc((size_t)N_NODES*64*2);
  bf16*  hp      = (bf16*) alloc((size_t)N_NODES*256*2);
  bf16*  outb    = (bf16*) alloc((size_t)N_NODES*256*2);   // bf16 activations

  bf16* out1 = outb;
  bf16* out2 = outb;                             // aliases (previous dead)
  bf16* out3 = outb + (size_t)N_NODES*64;
  bf16* out4 = outb + (size_t)N_NODES*128;
  float* bn1 = bnstat;
  float* bn2 = bnstat + 512;
  float* bn3 = bnstat + 640;
  float* bn4 = bnstat + 768;
  float* psum = pool;
  float* pcnt = pool + N_GRAPHS*64;

  const int segidx[NSEG] = {2, 5,6,7,8,9,10,11,12, 13,14,15,16,17,18,19,20,
                            21,22,23,24, 25,26,27,28, 29,30,31,32, 33,34,35,36};
  const int segn[NSEG] = {8192, 16384,256,256,2048,256,256,256,256,
                          16384,64,64,512,64,64,64,64,
                          4096,64,64,64, 4096,64,64,64,
                          2048,64,4096,64, 16384,128,128,1};
  Bank bk;
  int offs[NSEG]; int acc0 = 0;
  for(int i=0;i<NSEG;i++){ bk.p[i]=d_in[segidx[i]]; bk.n[i]=segn[i]; bk.off[i]=acc0; offs[i]=acc0; acc0+=segn[i]; }
  const float* f_exf = wbank + offs[0];
  const float* fW1 = wbank+offs[1]; const float* fas1 = wbank+offs[2]; const float* fad1 = wbank+offs[3];
  const float* fWe1= wbank+offs[4]; const float* fae1 = wbank+offs[5]; const float* fb1  = wbank+offs[6];
  const float* fg1 = wbank+offs[7]; const float* fbe1 = wbank+offs[8];
  const float* fW2 = wbank+offs[9]; const float* fas2 = wbank+offs[10]; const float* fad2 = wbank+offs[11];
  const float* fWe2= wbank+offs[12]; const float* fae2 = wbank+offs[13]; const float* fb2 = wbank+offs[14];
  const float* fg2 = wbank+offs[15]; const float* fbe2 = wbank+offs[16];
  const float* fWg1= wbank+offs[17]; const float* fbg1 = wbank+offs[18]; const float* fg3 = wbank+offs[19];
  const float* fbe3= wbank+offs[20];
  const float* fWg2= wbank+offs[21]; const float* fbg2 = wbank+offs[22]; const float* fg4 = wbank+offs[23];
  const float* fbe4= wbank+offs[24];
  const float* fWex1=wbank+offs[25]; const float* fbex1= wbank+offs[26];
  const float* fWex2=wbank+offs[27]; const float* fbex2= wbank+offs[28];
  const float* fWc1= wbank+offs[29]; const float* fbc1 = wbank+offs[30];
  const float* fWc2= wbank+offs[31]; const float* fbc2 = wbank+offs[32];

  const int nbN  = (N_NODES + 255)/256;
  const int nbE  = (N_EDGES + 255)/256;
  const int nbT  = (N_NODES + 63)/64;

  hipMemsetAsync(d_ws, 0, zbytes, stream);
  {
    dim3 g((16384+255)/256, NSEG);
    k_convert<<<g,256,0,stream>>>(bk, x, wbank);
  }
  k_cvt_x<<<(N_NODES*16+255)/256,256,0,stream>>>(x, xb);
  k_we<<<1,64,0,stream>>>(fWe1, fae1, fWe2, fae2, w_e);
  k_count<<<nbE,256,0,stream>>>(dst, cnt);
  k_blocksum<<<nbN,256,0,stream>>>(cnt, bsum);
  k_scan_bsum<<<1,256,0,stream>>>(bsum, bofs, nbN);
  k_scan_write<<<nbN,256,0,stream>>>(cnt, bofs, rp, dinv);
  k_fill<<<nbE,256,0,stream>>>(src, dst, rp, fill, ea, x, w_e, epk);

  // GAT layer 1 (4 heads via grid.y)
  {
    dim3 g(nbT, 4);
    k_gemmA<<<g,256,0,stream>>>(xb, fW1, hp, N_NODES);
  }
  k_al4<<<(N_NODES*4+255)/256,256,0,stream>>>(hp, fas1, fad1, als4, ald4);
  k_gat_agg4<<<N_NODES,64,0,stream>>>(rp, epk, hp, als4, ald4, fb1, out1);
  k_colstats<256><<<(N_NODES+127)/128,256,0,stream>>>(out1, bn1);

  // GAT layer 2 (1 head) — BN1+ReLU fused into A-staging
  k_gemmB<256><<<nbT,256,0,stream>>>(out1, fW2, hp, N_NODES, bn1, fg1, fbe1);
  k_al1<<<nbN,256,0,stream>>>(hp, fas2, fad2, als4, ald4);
  k_gat_agg1e<<<N_NODES,64,0,stream>>>(rp, epk, hp, als4, ald4, fb2, out2);
  k_colstats<64><<<(N_NODES+127)/128,256,0,stream>>>(out2, bn2);

  // GCN layer 1 — BN2+ReLU fused
  k_gemmB<64><<<nbT,256,0,stream>>>(out2, fWg1, hp, N_NODES, bn2, fg2, fbe2);
  k_gcn_agg<<<N_NODES,64,0,stream>>>(rp, epk, dinv, hp, fbg1, out3);
  k_colstats<64><<<(N_NODES+127)/128,256,0,stream>>>(out3, bn3);

  // GCN layer 2 — BN3+ReLU fused
  k_gemmB<64><<<nbT,256,0,stream>>>(out3, fWg2, hp, N_NODES, bn3, fg3, fbe3);
  k_gcn_agg<<<N_NODES,64,0,stream>>>(rp, epk, dinv, hp, fbg2, out4);
  k_colstats<64><<<(N_NODES+127)/128,256,0,stream>>>(out4, bn4);

  // pool (BN4+ReLU fused) + head
  k_pool3<<<nbN,64,0,stream>>>(out4, batch, bn4, fg4, fbe4, psum, pcnt);
  k_head<<<N_GRAPHS,128,0,stream>>>(psum, pcnt, f_exf, fWex1, fbex1, fWex2, fbex2,
                                    fWc1, fbc1, fWc2, fbc2, x, (void*)d_out);
}